// Round 1
// baseline (349.025 us; speedup 1.0000x reference)
//
#include <hip/hip_runtime.h>
#include <hip/hip_bf16.h>
#include <stdint.h>

#define NB   16384
#define DIN  1024
#define MPAD 16896   /* 16384 + 4*128 : per-domain segments padded to 128 */

typedef __bf16 bf16;
typedef __bf16 v8bf __attribute__((ext_vector_type(8)));
typedef float  v4f  __attribute__((ext_vector_type(4)));

typedef __attribute__((address_space(1))) void* as1_ptr;
typedef __attribute__((address_space(3))) void* as3_ptr;

__device__ __forceinline__ void gl_lds16(const void* g, void* l) {
  // async global->LDS, 16B per lane; LDS dest = wave-uniform base + lane*16
  __builtin_amdgcn_global_load_lds((as1_ptr)(g), (as3_ptr)(l), 16, 0, 0);
}

__device__ __forceinline__ unsigned short bfbits(float f) {
  bf16 h = (bf16)f;
  return __builtin_bit_cast(unsigned short, h);
}

// ---------------------------------------------------------------- init
__global__ void k_init(int* __restrict__ counts, int* __restrict__ perm) {
  int i = blockIdx.x * 256 + threadIdx.x;
  if (i < 8) counts[i] = 0;          // counts[4] + cnt2[4] contiguous
  if (i < MPAD) perm[i] = -1;
}

// ---------------------------------------------------------------- histogram
__global__ void k_hist(const int* __restrict__ dom, int* __restrict__ counts) {
  int i = blockIdx.x * 256 + threadIdx.x;   // grid covers exactly NB
  int lane = threadIdx.x & 63;
  int d = dom[i];
#pragma unroll
  for (int dd = 0; dd < 4; dd++) {
    unsigned long long m = __ballot(d == dd);
    if (lane == 0 && m) atomicAdd(&counts[dd], __popcll(m));
  }
}

// ---------------------------------------------------------------- scan + aux
__global__ void k_scan_aux(const int* __restrict__ counts, int* __restrict__ pstart,
                           float* __restrict__ aux,
                           const float* __restrict__ dom_emb, const float* __restrict__ aW1,
                           const float* __restrict__ ab1, const float* __restrict__ aW2,
                           const float* __restrict__ ab2) {
  int t = threadIdx.x;
  if (t == 0) {
    int p = 0;
    for (int d = 0; d < 4; d++) { pstart[d] = p; p += (counts[d] + 127) & ~127; }
    pstart[4] = p;
  }
  if (t < 4) {
    float a = ab2[0];
    for (int j = 0; j < 32; j++) {
      float s = ab1[j];
      for (int i = 0; i < 16; i++) s += dom_emb[t * 16 + i] * aW1[i * 32 + j];
      a += fmaxf(s, 0.f) * aW2[j];
    }
    aux[t] = a;
  }
}

// ---------------------------------------------------------------- assign sorted positions
__global__ void k_assign(const int* __restrict__ dom, const int* __restrict__ pstart,
                         int* __restrict__ cnt2, int* __restrict__ perm,
                         int* __restrict__ rowpos) {
  int i = blockIdx.x * 256 + threadIdx.x;
  int lane = threadIdx.x & 63;
  int d = dom[i];
  unsigned long long ltmask = (1ull << lane) - 1ull;
#pragma unroll
  for (int dd = 0; dd < 4; dd++) {
    unsigned long long m = __ballot(d == dd);
    int c = __popcll(m);
    int base = 0;
    if (lane == 0 && c) base = atomicAdd(&cnt2[dd], c);
    base = __shfl(base, 0, 64);
    if (d == dd) {
      int pos = pstart[dd] + base + __popcll(m & ltmask);
      perm[pos] = i;
      rowpos[i] = pos;
    }
  }
}

// ---------------------------------------------------------------- layernorm -> sorted bf16
__global__ __launch_bounds__(256) void k_ln(const float* __restrict__ x,
                                            const int* __restrict__ dom,
                                            const int* __restrict__ rowpos,
                                            const float* __restrict__ pn_w,
                                            const float* __restrict__ pn_b,
                                            bf16* __restrict__ norm) {
  int wv = threadIdx.x >> 6, lane = threadIdx.x & 63;
  int r = blockIdx.x * 4 + wv;                  // grid 4096 -> exactly NB rows
  const float* xr = x + (size_t)r * DIN;
  float4 v[4];
#pragma unroll
  for (int g = 0; g < 4; g++) v[g] = *(const float4*)(xr + g * 256 + lane * 4);
  float s = 0.f;
#pragma unroll
  for (int g = 0; g < 4; g++) s += v[g].x + v[g].y + v[g].z + v[g].w;
#pragma unroll
  for (int o = 32; o; o >>= 1) s += __shfl_xor(s, o, 64);
  float mean = s * (1.f / 1024.f);
  float q = 0.f;
#pragma unroll
  for (int g = 0; g < 4; g++) {
    float a = v[g].x - mean, b = v[g].y - mean, c = v[g].z - mean, e = v[g].w - mean;
    q += a * a + b * b + c * c + e * e;
  }
#pragma unroll
  for (int o = 32; o; o >>= 1) q += __shfl_xor(q, o, 64);
  float rstd = rsqrtf(q * (1.f / 1024.f) + 1e-5f);
  int d = dom[r];
  int pos = rowpos[r];
  const float* pw = pn_w + (size_t)d * DIN;
  const float* pb = pn_b + (size_t)d * DIN;
  bf16* orow = norm + (size_t)pos * DIN;
#pragma unroll
  for (int g = 0; g < 4; g++) {
    float4 w4 = *(const float4*)(pw + g * 256 + lane * 4);
    float4 b4 = *(const float4*)(pb + g * 256 + lane * 4);
    ushort4 o;
    o.x = bfbits((v[g].x - mean) * rstd * w4.x + b4.x);
    o.y = bfbits((v[g].y - mean) * rstd * w4.y + b4.y);
    o.z = bfbits((v[g].z - mean) * rstd * w4.z + b4.z);
    o.w = bfbits((v[g].w - mean) * rstd * w4.w + b4.w);
    *(ushort4*)(orow + g * 256 + lane * 4) = o;
  }
}

// ---------------------------------------------------------------- zero padding rows
__global__ void k_zeropad(const int* __restrict__ perm, bf16* __restrict__ norm) {
  int row = blockIdx.x;
  if (perm[row] >= 0) return;
  *(uint2*)(norm + (size_t)row * DIN + threadIdx.x * 4) = make_uint2(0u, 0u);
}

// ---------------------------------------------------------------- weight fp32 KxN -> bf16 NxK
__global__ void k_wt(const float* __restrict__ src, bf16* __restrict__ dst,
                     int K, int N, int total) {
  int i = blockIdx.x * 256 + threadIdx.x;
  if (i >= total) return;
  int kn = K * N;
  int b = i / kn;
  int rem = i - b * kn;
  int n = rem / K;
  int k = rem - n * K;
  dst[i] = (bf16)src[(size_t)b * kn + (size_t)k * N + n];
}

// ---------------------------------------------------------------- fused center|domain GEMM
// C[Mpad x 2*Nh] = A[Mpad x lda] (cols a_off.. ) @ [cWt | dWt[seg]]^T + bias, opt relu
__global__ __launch_bounds__(256) void k_gemm(const bf16* __restrict__ A, int lda,
                                              int aoffc, int aoffd,
                                              const bf16* __restrict__ cWt,
                                              const bf16* __restrict__ dWt,
                                              const float* __restrict__ cb,
                                              const float* __restrict__ db,
                                              bf16* __restrict__ C, int Nh, int Kd,
                                              int relu, const int* __restrict__ pstart) {
  __shared__ bf16 Al[128 * 64];
  __shared__ bf16 Bl[128 * 64];
  const int tid = threadIdx.x;
  const int wv = tid >> 6, lane = tid & 63;
  const int rt = blockIdx.y, ct = blockIdx.x;
  const int row0 = rt * 128;
  int d = 0;
  if (row0 >= pstart[1]) d = 1;
  if (row0 >= pstart[2]) d = 2;
  if (row0 >= pstart[3]) d = 3;
  const int n0 = ct * 128;
  const bool isd = (n0 >= Nh);
  const bf16* Wt = isd ? dWt + ((size_t)d * Nh + (n0 - Nh)) * Kd : cWt + (size_t)n0 * Kd;
  const float* bias = isd ? db + d * Nh + (n0 - Nh) : cb + n0;
  const int aoff = isd ? aoffd : aoffc;
  const bf16* Ab = A + (size_t)row0 * lda + aoff;

  v4f acc[4][4];
#pragma unroll
  for (int i = 0; i < 4; i++)
#pragma unroll
    for (int j = 0; j < 4; j++) acc[i][j] = v4f{0.f, 0.f, 0.f, 0.f};

  const int wm = (wv >> 1) * 64, wn = (wv & 1) * 64;
  const int mrow = lane & 15, quad = lane >> 4;
  const int lrow = lane >> 3;   // loader: row within 8-row group
  const int lchk = lane & 7;    // loader: LDS chunk slot
  const int ldc = 2 * Nh;

  for (int kt = 0; kt < Kd; kt += 64) {
#pragma unroll
    for (int p = 0; p < 4; p++) {
      int rbase = wv * 32 + p * 8;
      int r = rbase + lrow;
      int jg = lchk ^ (r & 7);  // XOR swizzle: G-chunk j stored at LDS chunk j^(r&7)
      gl_lds16(Ab + (size_t)r * lda + kt + jg * 8, &Al[rbase * 64]);
      gl_lds16(Wt + (size_t)r * Kd + kt + jg * 8, &Bl[rbase * 64]);
    }
    __syncthreads();
#pragma unroll
    for (int s = 0; s < 2; s++) {
      v8bf af[4], bfr[4];
#pragma unroll
      for (int mi = 0; mi < 4; mi++) {
        int m = wm + mi * 16 + mrow;
        int j = (s * 4 + quad) ^ (m & 7);
        af[mi] = *(const v8bf*)&Al[m * 64 + j * 8];
      }
#pragma unroll
      for (int ni = 0; ni < 4; ni++) {
        int n = wn + ni * 16 + mrow;
        int j = (s * 4 + quad) ^ (n & 7);
        bfr[ni] = *(const v8bf*)&Bl[n * 64 + j * 8];
      }
#pragma unroll
      for (int mi = 0; mi < 4; mi++)
#pragma unroll
        for (int ni = 0; ni < 4; ni++)
          acc[mi][ni] =
              __builtin_amdgcn_mfma_f32_16x16x32_bf16(af[mi], bfr[ni], acc[mi][ni], 0, 0, 0);
    }
    __syncthreads();
  }

  float bv[4];
#pragma unroll
  for (int ni = 0; ni < 4; ni++) bv[ni] = bias[wn + ni * 16 + mrow];
#pragma unroll
  for (int mi = 0; mi < 4; mi++) {
    int growb = row0 + wm + mi * 16 + quad * 4;
#pragma unroll
    for (int ni = 0; ni < 4; ni++) {
      int gcol = n0 + wn + ni * 16 + mrow;
#pragma unroll
      for (int r2 = 0; r2 < 4; r2++) {
        float v = acc[mi][ni][r2] + bv[ni];
        if (relu) v = fmaxf(v, 0.f);
        C[(size_t)(growb + r2) * ldc + gcol] = (bf16)v;
      }
    }
  }
}

// ---------------------------------------------------------------- head: fuse + 128->64->1
__global__ __launch_bounds__(256) void k_final(const bf16* __restrict__ h3,
                                               const int* __restrict__ perm,
                                               const int* __restrict__ pstart,
                                               const float* __restrict__ aux,
                                               const float* __restrict__ fW1,
                                               const float* __restrict__ fb1,
                                               const float* __restrict__ fW2,
                                               const float* __restrict__ fb2,
                                               float* __restrict__ out) {
  __shared__ float Wl[128 * 64];
  int tid = threadIdx.x;
  for (int i = tid; i < 128 * 64; i += 256) Wl[i] = fW1[i];
  __syncthreads();
  int wv = tid >> 6, lane = tid & 63;
  int p1 = pstart[1], p2 = pstart[2], p3 = pstart[3];
  float bias1 = fb1[lane];
  float w2 = fW2[lane];
  for (int pos = blockIdx.x * 4 + wv; pos < MPAD; pos += gridDim.x * 4) {
    int orig = perm[pos];
    if (orig < 0) continue;
    const bf16* hr = h3 + (size_t)pos * 256;
    float f0 = (float)hr[lane] * tanhf((float)hr[128 + lane]);
    float f1 = (float)hr[64 + lane] * tanhf((float)hr[192 + lane]);
    float acc = bias1;
#pragma unroll 16
    for (int i = 0; i < 64; i++) acc = fmaf(__shfl(f0, i, 64), Wl[i * 64 + lane], acc);
#pragma unroll 16
    for (int i = 0; i < 64; i++) acc = fmaf(__shfl(f1, i, 64), Wl[(64 + i) * 64 + lane], acc);
    float y = fmaxf(acc, 0.f) * w2;
#pragma unroll
    for (int o = 32; o; o >>= 1) y += __shfl_xor(y, o, 64);
    if (lane == 0) {
      int dd = (pos >= p1) + (pos >= p2) + (pos >= p3);
      float z = y + fb2[0] + aux[dd];
      out[orig] = 1.f / (1.f + expf(-z));
    }
  }
}

// ---------------------------------------------------------------- launch
extern "C" void kernel_launch(void* const* d_in, const int* in_sizes, int n_in,
                              void* d_out, int out_size, void* d_ws, size_t ws_size,
                              hipStream_t stream) {
  (void)in_sizes; (void)n_in; (void)out_size; (void)ws_size;
  const float* x      = (const float*)d_in[0];
  const int*   dom    = (const int*)d_in[1];
  const float* pn_w   = (const float*)d_in[2];
  const float* pn_b   = (const float*)d_in[3];
  const float* cW1    = (const float*)d_in[4];
  const float* cb1    = (const float*)d_in[5];
  const float* cW2    = (const float*)d_in[6];
  const float* cb2    = (const float*)d_in[7];
  const float* cW3    = (const float*)d_in[8];
  const float* cb3    = (const float*)d_in[9];
  const float* dW1    = (const float*)d_in[10];
  const float* db1    = (const float*)d_in[11];
  const float* dW2    = (const float*)d_in[12];
  const float* db2    = (const float*)d_in[13];
  const float* dW3    = (const float*)d_in[14];
  const float* db3    = (const float*)d_in[15];
  const float* fW1    = (const float*)d_in[16];
  const float* fb1    = (const float*)d_in[17];
  const float* fW2    = (const float*)d_in[18];
  const float* fb2    = (const float*)d_in[19];
  const float* demb   = (const float*)d_in[20];
  const float* aW1    = (const float*)d_in[21];
  const float* ab1    = (const float*)d_in[22];
  const float* aW2    = (const float*)d_in[23];
  const float* ab2    = (const float*)d_in[24];
  float* out = (float*)d_out;

  char* w = (char*)d_ws;
  int*   counts = (int*)(w + 0);        // [4]
  int*   cnt2   = (int*)(w + 16);       // [4]
  int*   pstart = (int*)(w + 32);       // [5]
  float* aux    = (float*)(w + 64);     // [4]
  int*   perm   = (int*)(w + 256);                     // [MPAD]
  int*   rowpos = (int*)(w + 67840);                   // [NB]
  bf16*  bufA   = (bf16*)(w + 133376);                 // norm (MPADx1024) then h2 (MPADx512)
  bf16*  bufB   = (bf16*)(w + 34736384);               // h1 (MPADx1024) then h3 (MPADx256)
  bf16*  cW1t   = (bf16*)(w + 69339392);
  bf16*  cW2t   = (bf16*)(w + 70387968);
  bf16*  cW3t   = (bf16*)(w + 70650112);
  bf16*  dW1t   = (bf16*)(w + 70715648);
  bf16*  dW2t   = (bf16*)(w + 74909952);
  bf16*  dW3t   = (bf16*)(w + 75958528);               // end: 76220672 bytes

  k_init<<<66, 256, 0, stream>>>(counts, perm);
  k_hist<<<64, 256, 0, stream>>>(dom, counts);
  k_scan_aux<<<1, 64, 0, stream>>>(counts, pstart, aux, demb, aW1, ab1, aW2, ab2);
  k_assign<<<64, 256, 0, stream>>>(dom, pstart, cnt2, perm, rowpos);
  k_ln<<<4096, 256, 0, stream>>>(x, dom, rowpos, pn_w, pn_b, bufA);
  k_zeropad<<<MPAD, 256, 0, stream>>>(perm, bufA);

  k_wt<<<2048, 256, 0, stream>>>(cW1, cW1t, 1024, 512, 524288);
  k_wt<<<512,  256, 0, stream>>>(cW2, cW2t, 512, 256, 131072);
  k_wt<<<128,  256, 0, stream>>>(cW3, cW3t, 256, 128, 32768);
  k_wt<<<8192, 256, 0, stream>>>(dW1, dW1t, 1024, 512, 2097152);
  k_wt<<<2048, 256, 0, stream>>>(dW2, dW2t, 512, 256, 524288);
  k_wt<<<512,  256, 0, stream>>>(dW3, dW3t, 256, 128, 131072);

  // L1: norm(bufA) -> h1(bufB) : K=1024, Nh=512, relu
  k_gemm<<<dim3(8, 132), 256, 0, stream>>>(bufA, 1024, 0, 0, cW1t, dW1t, cb1, db1,
                                           bufB, 512, 1024, 1, pstart);
  // L2: h1(bufB) -> h2(bufA) : K=512, Nh=256, relu; domain half reads cols 512..
  k_gemm<<<dim3(4, 132), 256, 0, stream>>>(bufB, 1024, 0, 512, cW2t, dW2t, cb2, db2,
                                           bufA, 256, 512, 1, pstart);
  // L3: h2(bufA) -> h3(bufB) : K=256, Nh=128, no relu; domain half reads cols 256..
  k_gemm<<<dim3(2, 132), 256, 0, stream>>>(bufA, 512, 0, 256, cW3t, dW3t, cb3, db3,
                                           bufB, 128, 256, 0, pstart);

  k_final<<<528, 256, 0, stream>>>(bufB, perm, pstart, aux, fW1, fb1, fW2, fb2, out);
}

// Round 2
// 343.896 us; speedup vs baseline: 1.0149x; 1.0149x over previous
//
#include <hip/hip_runtime.h>
#include <hip/hip_bf16.h>
#include <stdint.h>

#define NB   16384
#define DIN  1024
#define MPAD 16896   /* 16384 + 4*128 : per-domain segments padded to 128 */

typedef __bf16 bf16;
typedef __bf16 v8bf __attribute__((ext_vector_type(8)));
typedef float  v4f  __attribute__((ext_vector_type(4)));

typedef __attribute__((address_space(1))) void* as1_ptr;
typedef __attribute__((address_space(3))) void* as3_ptr;

__device__ __forceinline__ void gl_lds16(const void* g, void* l) {
  __builtin_amdgcn_global_load_lds((as1_ptr)(g), (as3_ptr)(l), 16, 0, 0);
}

__device__ __forceinline__ unsigned short bfbits(float f) {
  bf16 h = (bf16)f;
  return __builtin_bit_cast(unsigned short, h);
}

// ------------------------------------------------ histogram + scan + aux + perm init
__global__ __launch_bounds__(1024) void k_histscan_aux(
    const int* __restrict__ dom, int* __restrict__ pstart, int* __restrict__ cnt2,
    int* __restrict__ perm, float* __restrict__ aux,
    const float* __restrict__ dom_emb, const float* __restrict__ aW1,
    const float* __restrict__ ab1, const float* __restrict__ aW2,
    const float* __restrict__ ab2) {
  __shared__ int hist[4];
  int tid = threadIdx.x, lane = tid & 63;
  if (tid < 4) hist[tid] = 0;
  if (tid >= 8 && tid < 12) cnt2[tid - 8] = 0;
  // perm = -1 (pad sentinel)
  for (int j = tid; j < MPAD; j += 1024) perm[j] = -1;
  __syncthreads();
  int c0 = 0, c1 = 0, c2 = 0, c3 = 0;
#pragma unroll
  for (int it = 0; it < 16; it++) {
    int d = dom[it * 1024 + tid];
    c0 += (d == 0); c1 += (d == 1); c2 += (d == 2); c3 += (d == 3);
  }
#pragma unroll
  for (int o = 32; o; o >>= 1) {
    c0 += __shfl_xor(c0, o, 64); c1 += __shfl_xor(c1, o, 64);
    c2 += __shfl_xor(c2, o, 64); c3 += __shfl_xor(c3, o, 64);
  }
  if (lane == 0) {
    atomicAdd(&hist[0], c0); atomicAdd(&hist[1], c1);
    atomicAdd(&hist[2], c2); atomicAdd(&hist[3], c3);
  }
  __syncthreads();
  if (tid == 0) {
    int p = 0;
    for (int d = 0; d < 4; d++) { pstart[d] = p; p += (hist[d] + 127) & ~127; }
    pstart[4] = p;
  }
  if (tid < 4) {
    float a = ab2[0];
    for (int j = 0; j < 32; j++) {
      float s = ab1[j];
      for (int i = 0; i < 16; i++) s += dom_emb[tid * 16 + i] * aW1[i * 32 + j];
      a += fmaxf(s, 0.f) * aW2[j];
    }
    aux[tid] = a;
  }
}

// ------------------------------------------------ assign sorted positions
__global__ void k_assign(const int* __restrict__ dom, const int* __restrict__ pstart,
                         int* __restrict__ cnt2, int* __restrict__ perm,
                         int* __restrict__ rowpos) {
  int i = blockIdx.x * 256 + threadIdx.x;
  int lane = threadIdx.x & 63;
  int d = dom[i];
  unsigned long long ltmask = (1ull << lane) - 1ull;
#pragma unroll
  for (int dd = 0; dd < 4; dd++) {
    unsigned long long m = __ballot(d == dd);
    int c = __popcll(m);
    int base = 0;
    if (lane == 0 && c) base = atomicAdd(&cnt2[dd], c);
    base = __shfl(base, 0, 64);
    if (d == dd) {
      int pos = pstart[dd] + base + __popcll(m & ltmask);
      perm[pos] = i;
      rowpos[i] = pos;
    }
  }
}

// ------------------------------------------------ layernorm -> sorted bf16
__global__ __launch_bounds__(256) void k_ln(const float* __restrict__ x,
                                            const int* __restrict__ dom,
                                            const int* __restrict__ rowpos,
                                            const float* __restrict__ pn_w,
                                            const float* __restrict__ pn_b,
                                            bf16* __restrict__ norm) {
  int wv = threadIdx.x >> 6, lane = threadIdx.x & 63;
  int r = blockIdx.x * 4 + wv;
  const float* xr = x + (size_t)r * DIN;
  float4 v[4];
#pragma unroll
  for (int g = 0; g < 4; g++) v[g] = *(const float4*)(xr + g * 256 + lane * 4);
  float s = 0.f;
#pragma unroll
  for (int g = 0; g < 4; g++) s += v[g].x + v[g].y + v[g].z + v[g].w;
#pragma unroll
  for (int o = 32; o; o >>= 1) s += __shfl_xor(s, o, 64);
  float mean = s * (1.f / 1024.f);
  float q = 0.f;
#pragma unroll
  for (int g = 0; g < 4; g++) {
    float a = v[g].x - mean, b = v[g].y - mean, c = v[g].z - mean, e = v[g].w - mean;
    q += a * a + b * b + c * c + e * e;
  }
#pragma unroll
  for (int o = 32; o; o >>= 1) q += __shfl_xor(q, o, 64);
  float rstd = rsqrtf(q * (1.f / 1024.f) + 1e-5f);
  int d = dom[r];
  int pos = rowpos[r];
  const float* pw = pn_w + (size_t)d * DIN;
  const float* pb = pn_b + (size_t)d * DIN;
  bf16* orow = norm + (size_t)pos * DIN;
#pragma unroll
  for (int g = 0; g < 4; g++) {
    float4 w4 = *(const float4*)(pw + g * 256 + lane * 4);
    float4 b4 = *(const float4*)(pb + g * 256 + lane * 4);
    ushort4 o;
    o.x = bfbits((v[g].x - mean) * rstd * w4.x + b4.x);
    o.y = bfbits((v[g].y - mean) * rstd * w4.y + b4.y);
    o.z = bfbits((v[g].z - mean) * rstd * w4.z + b4.z);
    o.w = bfbits((v[g].w - mean) * rstd * w4.w + b4.w);
    *(ushort4*)(orow + g * 256 + lane * 4) = o;
  }
}

// ------------------------------------------------ fused LDS-tiled weight transpose
// 15 matrices (KxN fp32 -> NxK bf16), 64x64 tiles, 840 blocks total
__global__ __launch_bounds__(256) void k_wt_all(
    const float* __restrict__ cW1, const float* __restrict__ cW2,
    const float* __restrict__ cW3, const float* __restrict__ dW1,
    const float* __restrict__ dW2, const float* __restrict__ dW3,
    bf16* __restrict__ cW1t, bf16* __restrict__ cW2t, bf16* __restrict__ cW3t,
    bf16* __restrict__ dW1t, bf16* __restrict__ dW2t, bf16* __restrict__ dW3t) {
  __shared__ float t[64 * 65];
  int bid = blockIdx.x;
  const float* src; bf16* dst; int K, N, tile;
  if (bid < 640) {
    K = 1024; N = 512; int m = bid >> 7; tile = bid & 127;
    src = m == 0 ? cW1 : dW1 + (size_t)(m - 1) * 524288;
    dst = m == 0 ? cW1t : dW1t + (size_t)(m - 1) * 524288;
  } else if (bid < 800) {
    K = 512; N = 256; int m = (bid - 640) >> 5; tile = (bid - 640) & 31;
    src = m == 0 ? cW2 : dW2 + (size_t)(m - 1) * 131072;
    dst = m == 0 ? cW2t : dW2t + (size_t)(m - 1) * 131072;
  } else {
    K = 256; N = 128; int m = (bid - 800) >> 3; tile = (bid - 800) & 7;
    src = m == 0 ? cW3 : dW3 + (size_t)(m - 1) * 32768;
    dst = m == 0 ? cW3t : dW3t + (size_t)(m - 1) * 32768;
  }
  int ntn = N >> 6;
  int k0 = (tile / ntn) << 6, n0 = (tile % ntn) << 6;
  int tid = threadIdx.x;
  int r = tid >> 2, c4 = (tid & 3) << 4;
#pragma unroll
  for (int j4 = 0; j4 < 4; j4++) {
    float4 v = *(const float4*)(src + (size_t)(k0 + r) * N + n0 + c4 + j4 * 4);
    t[r * 65 + c4 + j4 * 4 + 0] = v.x;
    t[r * 65 + c4 + j4 * 4 + 1] = v.y;
    t[r * 65 + c4 + j4 * 4 + 2] = v.z;
    t[r * 65 + c4 + j4 * 4 + 3] = v.w;
  }
  __syncthreads();
  int n = tid >> 2, kc = (tid & 3) << 4;
#pragma unroll
  for (int j4 = 0; j4 < 4; j4++) {
    ushort4 o;
    o.x = bfbits(t[(kc + j4 * 4 + 0) * 65 + n]);
    o.y = bfbits(t[(kc + j4 * 4 + 1) * 65 + n]);
    o.z = bfbits(t[(kc + j4 * 4 + 2) * 65 + n]);
    o.w = bfbits(t[(kc + j4 * 4 + 3) * 65 + n]);
    *(ushort4*)(dst + (size_t)(n0 + n) * K + k0 + kc + j4 * 4) = o;
  }
}

// ------------------------------------------------ fused center|domain GEMM (L1, L2)
// XCD-swizzled 1D grid: same row-tile's column tiles share l mod 8 -> same XCD L2
__global__ __launch_bounds__(256) void k_gemm(const bf16* __restrict__ A, int lda,
                                              int aoffc, int aoffd,
                                              const bf16* __restrict__ cWt,
                                              const bf16* __restrict__ dWt,
                                              const float* __restrict__ cb,
                                              const float* __restrict__ db,
                                              bf16* __restrict__ C, int Nh, int Kd,
                                              int relu, const int* __restrict__ pstart,
                                              int lognct) {
  __shared__ bf16 Al[128 * 64];
  __shared__ bf16 Bl[128 * 64];
  const int tid = threadIdx.x;
  const int wv = tid >> 6, lane = tid & 63;
  const int nct = 1 << lognct;
  const int T1 = nct << 7;
  int l = blockIdx.x, rt, ct;
  if (l < T1) {
    int t = l >> 3;
    ct = t & (nct - 1);
    rt = ((t >> lognct) << 3) | (l & 7);
  } else {
    int l2 = l - T1;
    rt = 128 + (l2 >> lognct);
    ct = l2 & (nct - 1);
  }
  const int row0 = rt * 128;
  int d = 0;
  if (row0 >= pstart[1]) d = 1;
  if (row0 >= pstart[2]) d = 2;
  if (row0 >= pstart[3]) d = 3;
  const int n0 = ct * 128;
  const bool isd = (n0 >= Nh);
  const bf16* Wt = isd ? dWt + ((size_t)d * Nh + (n0 - Nh)) * Kd : cWt + (size_t)n0 * Kd;
  const float* bias = isd ? db + d * Nh + (n0 - Nh) : cb + n0;
  const int aoff = isd ? aoffd : aoffc;
  const bf16* Ab = A + (size_t)row0 * lda + aoff;

  v4f acc[4][4];
#pragma unroll
  for (int i = 0; i < 4; i++)
#pragma unroll
    for (int j = 0; j < 4; j++) acc[i][j] = v4f{0.f, 0.f, 0.f, 0.f};

  const int wm = (wv >> 1) * 64, wn = (wv & 1) * 64;
  const int mrow = lane & 15, quad = lane >> 4;
  const int lrow = lane >> 3;
  const int lchk = lane & 7;
  const int ldc = 2 * Nh;

  for (int kt = 0; kt < Kd; kt += 64) {
#pragma unroll
    for (int p = 0; p < 4; p++) {
      int rbase = wv * 32 + p * 8;
      int r = rbase + lrow;
      int jg = lchk ^ (r & 7);
      gl_lds16(Ab + (size_t)r * lda + kt + jg * 8, &Al[rbase * 64]);
      gl_lds16(Wt + (size_t)r * Kd + kt + jg * 8, &Bl[rbase * 64]);
    }
    __syncthreads();
#pragma unroll
    for (int s = 0; s < 2; s++) {
      v8bf af[4], bfr[4];
#pragma unroll
      for (int mi = 0; mi < 4; mi++) {
        int m = wm + mi * 16 + mrow;
        int j = (s * 4 + quad) ^ (m & 7);
        af[mi] = *(const v8bf*)&Al[m * 64 + j * 8];
      }
#pragma unroll
      for (int ni = 0; ni < 4; ni++) {
        int n = wn + ni * 16 + mrow;
        int j = (s * 4 + quad) ^ (n & 7);
        bfr[ni] = *(const v8bf*)&Bl[n * 64 + j * 8];
      }
#pragma unroll
      for (int mi = 0; mi < 4; mi++)
#pragma unroll
        for (int ni = 0; ni < 4; ni++)
          acc[mi][ni] =
              __builtin_amdgcn_mfma_f32_16x16x32_bf16(af[mi], bfr[ni], acc[mi][ni], 0, 0, 0);
    }
    __syncthreads();
  }

  float bv[4];
#pragma unroll
  for (int ni = 0; ni < 4; ni++) bv[ni] = bias[wn + ni * 16 + mrow];
#pragma unroll
  for (int mi = 0; mi < 4; mi++) {
    int growb = row0 + wm + mi * 16 + quad * 4;
#pragma unroll
    for (int ni = 0; ni < 4; ni++) {
      int gcol = n0 + wn + ni * 16 + mrow;
#pragma unroll
      for (int r2 = 0; r2 < 4; r2++) {
        float v = acc[mi][ni][r2] + bv[ni];
        if (relu) v = fmaxf(v, 0.f);
        C[(size_t)(growb + r2) * ldc + gcol] = (bf16)v;
      }
    }
  }
}

// ------------------------------------------------ L3 GEMM + fused head
// 64-row blocks; both center(128) and domain(128) h3 cols resident in LDS,
// head (fuse, 128->64->1, sigmoid) computed in-block, scattered to out.
__global__ __launch_bounds__(256) void k_gemm3(const bf16* __restrict__ A,
                                               const bf16* __restrict__ cW3t,
                                               const bf16* __restrict__ dW3t,
                                               const float* __restrict__ cb3,
                                               const float* __restrict__ db3,
                                               const int* __restrict__ perm,
                                               const int* __restrict__ pstart,
                                               const float* __restrict__ aux,
                                               const float* __restrict__ fW1,
                                               const float* __restrict__ fb1,
                                               const float* __restrict__ fW2,
                                               const float* __restrict__ fb2,
                                               float* __restrict__ out) {
  __shared__ bf16 Al[64 * 64];        // 8 KB
  __shared__ bf16 Bl[128 * 64];       // 16 KB
  __shared__ bf16 h3l[64 * 264];      // 33 KB (stride 264 breaks bank conflicts)
  __shared__ float fW1l[128 * 64];    // 32 KB
  const int tid = threadIdx.x, wv = tid >> 6, lane = tid & 63;
  for (int i = tid; i < 8192; i += 256) fW1l[i] = fW1[i];
  const int row0 = blockIdx.x * 64;
  const int d = (row0 >= pstart[1]) + (row0 >= pstart[2]) + (row0 >= pstart[3]);
  const bf16* Ab = A + (size_t)row0 * 512;
  const int mrow = lane & 15, quad = lane >> 4, lrow = lane >> 3, lchk = lane & 7;
  const int wm = (wv >> 1) * 32, wn = (wv & 1) * 64;

#pragma unroll
  for (int ph = 0; ph < 2; ph++) {
    const bf16* Wt = ph ? dW3t + (size_t)d * 32768 : cW3t;
    const float* bias = ph ? db3 + d * 128 : cb3;
    const int aoff = ph * 256;
    v4f acc[2][4];
#pragma unroll
    for (int i = 0; i < 2; i++)
#pragma unroll
      for (int j = 0; j < 4; j++) acc[i][j] = v4f{0.f, 0.f, 0.f, 0.f};
    for (int kt = 0; kt < 256; kt += 64) {
#pragma unroll
      for (int p = 0; p < 2; p++) {
        int rbase = wv * 16 + p * 8;
        int r = rbase + lrow;
        int jg = lchk ^ (r & 7);
        gl_lds16(Ab + (size_t)r * 512 + aoff + kt + jg * 8, &Al[rbase * 64]);
      }
#pragma unroll
      for (int p = 0; p < 4; p++) {
        int rbase = wv * 32 + p * 8;
        int r = rbase + lrow;
        int jg = lchk ^ (r & 7);
        gl_lds16(Wt + (size_t)r * 256 + kt + jg * 8, &Bl[rbase * 64]);
      }
      __syncthreads();
#pragma unroll
      for (int s = 0; s < 2; s++) {
        v8bf af[2], bfr[4];
#pragma unroll
        for (int mi = 0; mi < 2; mi++) {
          int m = wm + mi * 16 + mrow;
          int j = (s * 4 + quad) ^ (m & 7);
          af[mi] = *(const v8bf*)&Al[m * 64 + j * 8];
        }
#pragma unroll
        for (int ni = 0; ni < 4; ni++) {
          int n = wn + ni * 16 + mrow;
          int j = (s * 4 + quad) ^ (n & 7);
          bfr[ni] = *(const v8bf*)&Bl[n * 64 + j * 8];
        }
#pragma unroll
        for (int mi = 0; mi < 2; mi++)
#pragma unroll
          for (int ni = 0; ni < 4; ni++)
            acc[mi][ni] =
                __builtin_amdgcn_mfma_f32_16x16x32_bf16(af[mi], bfr[ni], acc[mi][ni], 0, 0, 0);
      }
      __syncthreads();
    }
#pragma unroll
    for (int mi = 0; mi < 2; mi++) {
      int rowb = wm + mi * 16 + quad * 4;
#pragma unroll
      for (int ni = 0; ni < 4; ni++) {
        int col = ph * 128 + wn + ni * 16 + mrow;
        float bv = bias[wn + ni * 16 + mrow];
#pragma unroll
        for (int r2 = 0; r2 < 4; r2++)
          h3l[(rowb + r2) * 264 + col] = (bf16)(acc[mi][ni][r2] + bv);
      }
    }
  }
  __syncthreads();

  // head: wave wv handles rows wv*16 .. wv*16+15
  const float b1 = fb1[lane], w2 = fW2[lane];
  const float addc = fb2[0] + aux[d];
  for (int i = 0; i < 16; i++) {
    int r = wv * 16 + i;
    int orig = perm[row0 + r];
    if (orig < 0) continue;
    const bf16* hr = &h3l[r * 264];
    float f0 = (float)hr[lane] * tanhf((float)hr[128 + lane]);
    float f1 = (float)hr[64 + lane] * tanhf((float)hr[192 + lane]);
    float acc = b1;
#pragma unroll 16
    for (int i2 = 0; i2 < 64; i2++) acc = fmaf(__shfl(f0, i2, 64), fW1l[i2 * 64 + lane], acc);
#pragma unroll 16
    for (int i2 = 0; i2 < 64; i2++)
      acc = fmaf(__shfl(f1, i2, 64), fW1l[(64 + i2) * 64 + lane], acc);
    float y = fmaxf(acc, 0.f) * w2;
#pragma unroll
    for (int o = 32; o; o >>= 1) y += __shfl_xor(y, o, 64);
    if (lane == 0) {
      float z = y + addc;
      out[orig] = 1.f / (1.f + expf(-z));
    }
  }
}

// ------------------------------------------------ launch
extern "C" void kernel_launch(void* const* d_in, const int* in_sizes, int n_in,
                              void* d_out, int out_size, void* d_ws, size_t ws_size,
                              hipStream_t stream) {
  (void)in_sizes; (void)n_in; (void)out_size; (void)ws_size;
  const float* x      = (const float*)d_in[0];
  const int*   dom    = (const int*)d_in[1];
  const float* pn_w   = (const float*)d_in[2];
  const float* pn_b   = (const float*)d_in[3];
  const float* cW1    = (const float*)d_in[4];
  const float* cb1    = (const float*)d_in[5];
  const float* cW2    = (const float*)d_in[6];
  const float* cb2    = (const float*)d_in[7];
  const float* cW3    = (const float*)d_in[8];
  const float* cb3    = (const float*)d_in[9];
  const float* dW1    = (const float*)d_in[10];
  const float* db1    = (const float*)d_in[11];
  const float* dW2    = (const float*)d_in[12];
  const float* db2    = (const float*)d_in[13];
  const float* dW3    = (const float*)d_in[14];
  const float* db3    = (const float*)d_in[15];
  const float* fW1    = (const float*)d_in[16];
  const float* fb1    = (const float*)d_in[17];
  const float* fW2    = (const float*)d_in[18];
  const float* fb2    = (const float*)d_in[19];
  const float* demb   = (const float*)d_in[20];
  const float* aW1    = (const float*)d_in[21];
  const float* ab1    = (const float*)d_in[22];
  const float* aW2    = (const float*)d_in[23];
  const float* ab2    = (const float*)d_in[24];
  float* out = (float*)d_out;

  char* w = (char*)d_ws;
  int*   cnt2   = (int*)(w + 16);       // [4]
  int*   pstart = (int*)(w + 32);       // [5]
  float* aux    = (float*)(w + 64);     // [4]
  int*   perm   = (int*)(w + 256);                     // [MPAD]
  int*   rowpos = (int*)(w + 67840);                   // [NB]
  bf16*  bufA   = (bf16*)(w + 133376);                 // norm (MPADx1024) then h2 (MPADx512)
  bf16*  bufB   = (bf16*)(w + 34736384);               // h1 (MPADx1024)
  bf16*  cW1t   = (bf16*)(w + 69339392);
  bf16*  cW2t   = (bf16*)(w + 70387968);
  bf16*  cW3t   = (bf16*)(w + 70650112);
  bf16*  dW1t   = (bf16*)(w + 70715648);
  bf16*  dW2t   = (bf16*)(w + 74909952);
  bf16*  dW3t   = (bf16*)(w + 75958528);               // end: 76220672 bytes

  k_histscan_aux<<<1, 1024, 0, stream>>>(dom, pstart, cnt2, perm, aux,
                                         demb, aW1, ab1, aW2, ab2);
  k_assign<<<64, 256, 0, stream>>>(dom, pstart, cnt2, perm, rowpos);
  k_ln<<<4096, 256, 0, stream>>>(x, dom, rowpos, pn_w, pn_b, bufA);
  k_wt_all<<<840, 256, 0, stream>>>(cW1, cW2, cW3, dW1, dW2, dW3,
                                    cW1t, cW2t, cW3t, dW1t, dW2t, dW3t);

  // L1: norm(bufA) -> h1(bufB) : K=1024, Nh=512, relu, 8 col tiles
  k_gemm<<<1056, 256, 0, stream>>>(bufA, 1024, 0, 0, cW1t, dW1t, cb1, db1,
                                   bufB, 512, 1024, 1, pstart, 3);
  // L2: h1(bufB) -> h2(bufA) : K=512, Nh=256, relu, 4 col tiles
  k_gemm<<<528, 256, 0, stream>>>(bufB, 1024, 0, 512, cW2t, dW2t, cb2, db2,
                                  bufA, 256, 512, 1, pstart, 2);
  // L3 + head fused: h2(bufA) -> out
  k_gemm3<<<264, 256, 0, stream>>>(bufA, cW3t, dW3t, cb3, db3, perm, pstart, aux,
                                   fW1, fb1, fW2, fb2, out);
}

// Round 3
// 267.554 us; speedup vs baseline: 1.3045x; 1.2853x over previous
//
#include <hip/hip_runtime.h>
#include <hip/hip_bf16.h>
#include <stdint.h>

#define NB   16384
#define DIN  1024
#define MPAD 16896   /* 16384 + 4*128 : per-domain segments padded to 128 */

typedef __bf16 bf16;
typedef __bf16 v8bf __attribute__((ext_vector_type(8)));
typedef float  v4f  __attribute__((ext_vector_type(4)));

typedef __attribute__((address_space(1))) void* as1_ptr;
typedef __attribute__((address_space(3))) void* as3_ptr;

__device__ __forceinline__ void gl_lds16(const void* g, void* l) {
  __builtin_amdgcn_global_load_lds((as1_ptr)(g), (as3_ptr)(l), 16, 0, 0);
}

__device__ __forceinline__ unsigned short bfbits(float f) {
  bf16 h = (bf16)f;
  return __builtin_bit_cast(unsigned short, h);
}

// ------------------------------------------------ histogram + scan + aux + perm init
__global__ __launch_bounds__(1024) void k_histscan_aux(
    const int* __restrict__ dom, int* __restrict__ pstart, int* __restrict__ cnt2,
    int* __restrict__ perm, float* __restrict__ aux,
    const float* __restrict__ dom_emb, const float* __restrict__ aW1,
    const float* __restrict__ ab1, const float* __restrict__ aW2,
    const float* __restrict__ ab2) {
  __shared__ int hist[4];
  int tid = threadIdx.x, lane = tid & 63;
  if (tid < 4) hist[tid] = 0;
  if (tid >= 8 && tid < 12) cnt2[tid - 8] = 0;
  for (int j = tid; j < MPAD; j += 1024) perm[j] = -1;
  __syncthreads();
  int c0 = 0, c1 = 0, c2 = 0, c3 = 0;
#pragma unroll
  for (int it = 0; it < 16; it++) {
    int d = dom[it * 1024 + tid];
    c0 += (d == 0); c1 += (d == 1); c2 += (d == 2); c3 += (d == 3);
  }
#pragma unroll
  for (int o = 32; o; o >>= 1) {
    c0 += __shfl_xor(c0, o, 64); c1 += __shfl_xor(c1, o, 64);
    c2 += __shfl_xor(c2, o, 64); c3 += __shfl_xor(c3, o, 64);
  }
  if (lane == 0) {
    atomicAdd(&hist[0], c0); atomicAdd(&hist[1], c1);
    atomicAdd(&hist[2], c2); atomicAdd(&hist[3], c3);
  }
  __syncthreads();
  if (tid == 0) {
    int p = 0;
    for (int d = 0; d < 4; d++) { pstart[d] = p; p += (hist[d] + 127) & ~127; }
    pstart[4] = p;
  }
  if (tid < 4) {
    float a = ab2[0];
    for (int j = 0; j < 32; j++) {
      float s = ab1[j];
      for (int i = 0; i < 16; i++) s += dom_emb[tid * 16 + i] * aW1[i * 32 + j];
      a += fmaxf(s, 0.f) * aW2[j];
    }
    aux[tid] = a;
  }
}

// ------------------------------------------------ assign sorted positions
__global__ void k_assign(const int* __restrict__ dom, const int* __restrict__ pstart,
                         int* __restrict__ cnt2, int* __restrict__ perm,
                         int* __restrict__ rowpos) {
  int i = blockIdx.x * 256 + threadIdx.x;
  int lane = threadIdx.x & 63;
  int d = dom[i];
  unsigned long long ltmask = (1ull << lane) - 1ull;
#pragma unroll
  for (int dd = 0; dd < 4; dd++) {
    unsigned long long m = __ballot(d == dd);
    int c = __popcll(m);
    int base = 0;
    if (lane == 0 && c) base = atomicAdd(&cnt2[dd], c);
    base = __shfl(base, 0, 64);
    if (d == dd) {
      int pos = pstart[dd] + base + __popcll(m & ltmask);
      perm[pos] = i;
      rowpos[i] = pos;
    }
  }
}

// ------------------------------------------------ layernorm -> sorted bf16
__global__ __launch_bounds__(256) void k_ln(const float* __restrict__ x,
                                            const int* __restrict__ dom,
                                            const int* __restrict__ rowpos,
                                            const float* __restrict__ pn_w,
                                            const float* __restrict__ pn_b,
                                            bf16* __restrict__ norm) {
  int wv = threadIdx.x >> 6, lane = threadIdx.x & 63;
  int r = blockIdx.x * 4 + wv;
  const float* xr = x + (size_t)r * DIN;
  float4 v[4];
#pragma unroll
  for (int g = 0; g < 4; g++) v[g] = *(const float4*)(xr + g * 256 + lane * 4);
  float s = 0.f;
#pragma unroll
  for (int g = 0; g < 4; g++) s += v[g].x + v[g].y + v[g].z + v[g].w;
#pragma unroll
  for (int o = 32; o; o >>= 1) s += __shfl_xor(s, o, 64);
  float mean = s * (1.f / 1024.f);
  float q = 0.f;
#pragma unroll
  for (int g = 0; g < 4; g++) {
    float a = v[g].x - mean, b = v[g].y - mean, c = v[g].z - mean, e = v[g].w - mean;
    q += a * a + b * b + c * c + e * e;
  }
#pragma unroll
  for (int o = 32; o; o >>= 1) q += __shfl_xor(q, o, 64);
  float rstd = rsqrtf(q * (1.f / 1024.f) + 1e-5f);
  int d = dom[r];
  int pos = rowpos[r];
  const float* pw = pn_w + (size_t)d * DIN;
  const float* pb = pn_b + (size_t)d * DIN;
  bf16* orow = norm + (size_t)pos * DIN;
#pragma unroll
  for (int g = 0; g < 4; g++) {
    float4 w4 = *(const float4*)(pw + g * 256 + lane * 4);
    float4 b4 = *(const float4*)(pb + g * 256 + lane * 4);
    ushort4 o;
    o.x = bfbits((v[g].x - mean) * rstd * w4.x + b4.x);
    o.y = bfbits((v[g].y - mean) * rstd * w4.y + b4.y);
    o.z = bfbits((v[g].z - mean) * rstd * w4.z + b4.z);
    o.w = bfbits((v[g].w - mean) * rstd * w4.w + b4.w);
    *(ushort4*)(orow + g * 256 + lane * 4) = o;
  }
}

// ------------------------------------------------ fused LDS-tiled weight transpose
// 16 matrices (KxN fp32 -> NxK bf16), 64x64 tiles, 842 blocks total
__global__ __launch_bounds__(256) void k_wt_all(
    const float* __restrict__ cW1, const float* __restrict__ cW2,
    const float* __restrict__ cW3, const float* __restrict__ dW1,
    const float* __restrict__ dW2, const float* __restrict__ dW3,
    const float* __restrict__ fW1,
    bf16* __restrict__ cW1t, bf16* __restrict__ cW2t, bf16* __restrict__ cW3t,
    bf16* __restrict__ dW1t, bf16* __restrict__ dW2t, bf16* __restrict__ dW3t,
    bf16* __restrict__ fW1t) {
  __shared__ float t[64 * 65];
  int bid = blockIdx.x;
  const float* src; bf16* dst; int K, N, tile;
  if (bid < 640) {
    K = 1024; N = 512; int m = bid >> 7; tile = bid & 127;
    src = m == 0 ? cW1 : dW1 + (size_t)(m - 1) * 524288;
    dst = m == 0 ? cW1t : dW1t + (size_t)(m - 1) * 524288;
  } else if (bid < 800) {
    K = 512; N = 256; int m = (bid - 640) >> 5; tile = (bid - 640) & 31;
    src = m == 0 ? cW2 : dW2 + (size_t)(m - 1) * 131072;
    dst = m == 0 ? cW2t : dW2t + (size_t)(m - 1) * 131072;
  } else if (bid < 840) {
    K = 256; N = 128; int m = (bid - 800) >> 3; tile = (bid - 800) & 7;
    src = m == 0 ? cW3 : dW3 + (size_t)(m - 1) * 32768;
    dst = m == 0 ? cW3t : dW3t + (size_t)(m - 1) * 32768;
  } else {
    K = 128; N = 64; tile = bid - 840;   // 2 tiles
    src = fW1; dst = fW1t;
  }
  int ntn = N >> 6;
  int k0 = (tile / ntn) << 6, n0 = (tile % ntn) << 6;
  int tid = threadIdx.x;
  int r = tid >> 2, c4 = (tid & 3) << 4;
#pragma unroll
  for (int j4 = 0; j4 < 4; j4++) {
    float4 v = *(const float4*)(src + (size_t)(k0 + r) * N + n0 + c4 + j4 * 4);
    t[r * 65 + c4 + j4 * 4 + 0] = v.x;
    t[r * 65 + c4 + j4 * 4 + 1] = v.y;
    t[r * 65 + c4 + j4 * 4 + 2] = v.z;
    t[r * 65 + c4 + j4 * 4 + 3] = v.w;
  }
  __syncthreads();
  int n = tid >> 2, kc = (tid & 3) << 4;
#pragma unroll
  for (int j4 = 0; j4 < 4; j4++) {
    ushort4 o;
    o.x = bfbits(t[(kc + j4 * 4 + 0) * 65 + n]);
    o.y = bfbits(t[(kc + j4 * 4 + 1) * 65 + n]);
    o.z = bfbits(t[(kc + j4 * 4 + 2) * 65 + n]);
    o.w = bfbits(t[(kc + j4 * 4 + 3) * 65 + n]);
    *(ushort4*)(dst + (size_t)(n0 + n) * K + k0 + kc + j4 * 4) = o;
  }
}

// ------------------------------------------------ fused center|domain GEMM (L1, L2)
__global__ __launch_bounds__(256) void k_gemm(const bf16* __restrict__ A, int lda,
                                              int aoffc, int aoffd,
                                              const bf16* __restrict__ cWt,
                                              const bf16* __restrict__ dWt,
                                              const float* __restrict__ cb,
                                              const float* __restrict__ db,
                                              bf16* __restrict__ C, int Nh, int Kd,
                                              int relu, const int* __restrict__ pstart,
                                              int lognct) {
  __shared__ bf16 Al[128 * 64];
  __shared__ bf16 Bl[128 * 64];
  const int tid = threadIdx.x;
  const int wv = tid >> 6, lane = tid & 63;
  const int nct = 1 << lognct;
  const int T1 = nct << 7;
  int l = blockIdx.x, rt, ct;
  if (l < T1) {
    int t = l >> 3;
    ct = t & (nct - 1);
    rt = ((t >> lognct) << 3) | (l & 7);
  } else {
    int l2 = l - T1;
    rt = 128 + (l2 >> lognct);
    ct = l2 & (nct - 1);
  }
  const int row0 = rt * 128;
  int d = 0;
  if (row0 >= pstart[1]) d = 1;
  if (row0 >= pstart[2]) d = 2;
  if (row0 >= pstart[3]) d = 3;
  const int n0 = ct * 128;
  const bool isd = (n0 >= Nh);
  const bf16* Wt = isd ? dWt + ((size_t)d * Nh + (n0 - Nh)) * Kd : cWt + (size_t)n0 * Kd;
  const float* bias = isd ? db + d * Nh + (n0 - Nh) : cb + n0;
  const int aoff = isd ? aoffd : aoffc;
  const bf16* Ab = A + (size_t)row0 * lda + aoff;

  v4f acc[4][4];
#pragma unroll
  for (int i = 0; i < 4; i++)
#pragma unroll
    for (int j = 0; j < 4; j++) acc[i][j] = v4f{0.f, 0.f, 0.f, 0.f};

  const int wm = (wv >> 1) * 64, wn = (wv & 1) * 64;
  const int mrow = lane & 15, quad = lane >> 4;
  const int lrow = lane >> 3;
  const int lchk = lane & 7;
  const int ldc = 2 * Nh;

  for (int kt = 0; kt < Kd; kt += 64) {
#pragma unroll
    for (int p = 0; p < 4; p++) {
      int rbase = wv * 32 + p * 8;
      int r = rbase + lrow;
      int jg = lchk ^ (r & 7);
      gl_lds16(Ab + (size_t)r * lda + kt + jg * 8, &Al[rbase * 64]);
      gl_lds16(Wt + (size_t)r * Kd + kt + jg * 8, &Bl[rbase * 64]);
    }
    __syncthreads();
#pragma unroll
    for (int s = 0; s < 2; s++) {
      v8bf af[4], bfr[4];
#pragma unroll
      for (int mi = 0; mi < 4; mi++) {
        int m = wm + mi * 16 + mrow;
        int j = (s * 4 + quad) ^ (m & 7);
        af[mi] = *(const v8bf*)&Al[m * 64 + j * 8];
      }
#pragma unroll
      for (int ni = 0; ni < 4; ni++) {
        int n = wn + ni * 16 + mrow;
        int j = (s * 4 + quad) ^ (n & 7);
        bfr[ni] = *(const v8bf*)&Bl[n * 64 + j * 8];
      }
#pragma unroll
      for (int mi = 0; mi < 4; mi++)
#pragma unroll
        for (int ni = 0; ni < 4; ni++)
          acc[mi][ni] =
              __builtin_amdgcn_mfma_f32_16x16x32_bf16(af[mi], bfr[ni], acc[mi][ni], 0, 0, 0);
    }
    __syncthreads();
  }

  float bv[4];
#pragma unroll
  for (int ni = 0; ni < 4; ni++) bv[ni] = bias[wn + ni * 16 + mrow];
#pragma unroll
  for (int mi = 0; mi < 4; mi++) {
    int growb = row0 + wm + mi * 16 + quad * 4;
#pragma unroll
    for (int ni = 0; ni < 4; ni++) {
      int gcol = n0 + wn + ni * 16 + mrow;
#pragma unroll
      for (int r2 = 0; r2 < 4; r2++) {
        float v = acc[mi][ni][r2] + bv[ni];
        if (relu) v = fmaxf(v, 0.f);
        C[(size_t)(growb + r2) * ldc + gcol] = (bf16)v;
      }
    }
  }
}

// ------------------------------------------------ L3 GEMM + MFMA head, all in registers/LDS
// 64-row blocks. Phase 0: h_center acc; phase 1: h_domain acc; epilogue computes
// fused = (hC+cb3)*tanh(hD+db3) -> swizzled LDS tile; head 128->64 via MFMA,
// relu*fW2 row-reduction cross-lane, sigmoid, scatter.
__global__ __launch_bounds__(256) void k_gemm3(const bf16* __restrict__ A,
                                               const bf16* __restrict__ cW3t,
                                               const bf16* __restrict__ dW3t,
                                               const float* __restrict__ cb3,
                                               const float* __restrict__ db3,
                                               const bf16* __restrict__ fW1t,
                                               const float* __restrict__ fb1,
                                               const float* __restrict__ fW2,
                                               const float* __restrict__ fb2,
                                               const int* __restrict__ perm,
                                               const int* __restrict__ pstart,
                                               const float* __restrict__ aux,
                                               float* __restrict__ out) {
  __shared__ __align__(16) bf16 Al[64 * 64];       // 8 KB
  __shared__ __align__(16) bf16 Bl[128 * 64];      // 16 KB
  __shared__ __align__(16) bf16 fusedL[64 * 128];  // 16 KB, XOR-swizzled chunks
  __shared__ __align__(16) bf16 fwB[64 * 128];     // 16 KB, XOR-swizzled chunks
  const int tid = threadIdx.x, wv = tid >> 6, lane = tid & 63;
  const int row0 = blockIdx.x * 64;
  const int d = (row0 >= pstart[1]) + (row0 >= pstart[2]) + (row0 >= pstart[3]);
  const bf16* Ab = A + (size_t)row0 * 512;
  const int mrow = lane & 15, quad = lane >> 4, lrow = lane >> 3, lchk = lane & 7;
  const int wm = (wv >> 1) * 32, wn = (wv & 1) * 64;

  // stage fW1t (64 N-rows x 128 K) into fwB, swizzled: chunk c at row holds
  // global chunk g = (c&8)|((c^row)&7)
  {
    int c = lane & 15, rsub = lane >> 4;
#pragma unroll
    for (int p = 0; p < 1; p++) {
      int rbase = wv * 16 + p * 4 * 4;   // wave wv covers rows wv*16..wv*16+15 in 4 instrs
      (void)rbase;
    }
#pragma unroll
    for (int p = 0; p < 4; p++) {
      int rbase = wv * 16 + p * 4;
      int row = rbase + rsub;
      int g = (c & 8) | ((c ^ row) & 7);
      gl_lds16(fW1t + row * 128 + g * 8, &fwB[rbase * 128]);
    }
  }

  v4f accC[2][4], accD[2][4];
#pragma unroll
  for (int i = 0; i < 2; i++)
#pragma unroll
    for (int j = 0; j < 4; j++) { accC[i][j] = v4f{0.f,0.f,0.f,0.f}; accD[i][j] = v4f{0.f,0.f,0.f,0.f}; }

#pragma unroll
  for (int ph = 0; ph < 2; ph++) {
    const bf16* Wt = ph ? dW3t + (size_t)d * 32768 : cW3t;
    const int aoff = ph * 256;
    for (int kt = 0; kt < 256; kt += 64) {
#pragma unroll
      for (int p = 0; p < 2; p++) {
        int rbase = wv * 16 + p * 8;
        int r = rbase + lrow;
        int jg = lchk ^ (r & 7);
        gl_lds16(Ab + (size_t)r * 512 + aoff + kt + jg * 8, &Al[rbase * 64]);
      }
#pragma unroll
      for (int p = 0; p < 4; p++) {
        int rbase = wv * 32 + p * 8;
        int r = rbase + lrow;
        int jg = lchk ^ (r & 7);
        gl_lds16(Wt + (size_t)r * 256 + kt + jg * 8, &Bl[rbase * 64]);
      }
      __syncthreads();
#pragma unroll
      for (int s = 0; s < 2; s++) {
        v8bf af[2], bfr[4];
#pragma unroll
        for (int mi = 0; mi < 2; mi++) {
          int m = wm + mi * 16 + mrow;
          int j = (s * 4 + quad) ^ (m & 7);
          af[mi] = *(const v8bf*)&Al[m * 64 + j * 8];
        }
#pragma unroll
        for (int ni = 0; ni < 4; ni++) {
          int n = wn + ni * 16 + mrow;
          int j = (s * 4 + quad) ^ (n & 7);
          bfr[ni] = *(const v8bf*)&Bl[n * 64 + j * 8];
        }
        if (ph == 0) {
#pragma unroll
          for (int mi = 0; mi < 2; mi++)
#pragma unroll
            for (int ni = 0; ni < 4; ni++)
              accC[mi][ni] = __builtin_amdgcn_mfma_f32_16x16x32_bf16(af[mi], bfr[ni], accC[mi][ni], 0, 0, 0);
        } else {
#pragma unroll
          for (int mi = 0; mi < 2; mi++)
#pragma unroll
            for (int ni = 0; ni < 4; ni++)
              accD[mi][ni] = __builtin_amdgcn_mfma_f32_16x16x32_bf16(af[mi], bfr[ni], accD[mi][ni], 0, 0, 0);
        }
      }
      __syncthreads();
    }
  }

  // epilogue: fused = (hC + cb3) * tanh(hD + db3), write swizzled into fusedL
#pragma unroll
  for (int mi = 0; mi < 2; mi++) {
    int rowb = wm + mi * 16 + quad * 4;
#pragma unroll
    for (int ni = 0; ni < 4; ni++) {
      int col = wn + ni * 16 + mrow;
      float cbv = cb3[col];
      float dbv = db3[d * 128 + col];
      int jc = col >> 3, coff = col & 7;
#pragma unroll
      for (int r2 = 0; r2 < 4; r2++) {
        int rr = rowb + r2;
        float f = (accC[mi][ni][r2] + cbv) * tanhf(accD[mi][ni][r2] + dbv);
        int cs = (jc & 8) | ((jc ^ rr) & 7);
        fusedL[rr * 128 + cs * 8 + coff] = (bf16)f;
      }
    }
  }
  __syncthreads();

  // head: wave wv computes rows wv*16..+15, all 64 neurons, via MFMA (K=128)
  float fb1v[4], fW2v[4];
#pragma unroll
  for (int nt = 0; nt < 4; nt++) {
    int col = nt * 16 + mrow;
    fb1v[nt] = fb1[col];
    fW2v[nt] = fW2[col];
  }
  v4f hacc[4];
#pragma unroll
  for (int nt = 0; nt < 4; nt++) hacc[nt] = v4f{0.f, 0.f, 0.f, 0.f};
  const int m = wv * 16 + mrow;
#pragma unroll
  for (int s = 0; s < 4; s++) {
    int j = s * 4 + quad;
    int ca = (j & 8) | ((j ^ m) & 7);
    v8bf af = *(const v8bf*)&fusedL[m * 128 + ca * 8];
#pragma unroll
    for (int nt = 0; nt < 4; nt++) {
      int n = nt * 16 + mrow;
      int cbk = (j & 8) | ((j ^ n) & 7);
      v8bf bfr = *(const v8bf*)&fwB[n * 128 + cbk * 8];
      hacc[nt] = __builtin_amdgcn_mfma_f32_16x16x32_bf16(af, bfr, hacc[nt], 0, 0, 0);
    }
  }
  // y[row] = sum_col relu(c+fb1)*fW2 ; cols live across the 16 lanes of each quad
  float ys[4];
#pragma unroll
  for (int r2 = 0; r2 < 4; r2++) {
    float s = 0.f;
#pragma unroll
    for (int nt = 0; nt < 4; nt++) s += fmaxf(hacc[nt][r2] + fb1v[nt], 0.f) * fW2v[nt];
    ys[r2] = s;
  }
#pragma unroll
  for (int o = 1; o < 16; o <<= 1)
#pragma unroll
    for (int r2 = 0; r2 < 4; r2++) ys[r2] += __shfl_xor(ys[r2], o, 64);
  if (mrow == 0) {
    const float addc = fb2[0] + aux[d];
#pragma unroll
    for (int r2 = 0; r2 < 4; r2++) {
      int prow = row0 + wv * 16 + quad * 4 + r2;
      int orig = perm[prow];
      if (orig >= 0) out[orig] = 1.f / (1.f + expf(-(ys[r2] + addc)));
    }
  }
}

// ------------------------------------------------ launch
extern "C" void kernel_launch(void* const* d_in, const int* in_sizes, int n_in,
                              void* d_out, int out_size, void* d_ws, size_t ws_size,
                              hipStream_t stream) {
  (void)in_sizes; (void)n_in; (void)out_size; (void)ws_size;
  const float* x      = (const float*)d_in[0];
  const int*   dom    = (const int*)d_in[1];
  const float* pn_w   = (const float*)d_in[2];
  const float* pn_b   = (const float*)d_in[3];
  const float* cW1    = (const float*)d_in[4];
  const float* cb1    = (const float*)d_in[5];
  const float* cW2    = (const float*)d_in[6];
  const float* cb2    = (const float*)d_in[7];
  const float* cW3    = (const float*)d_in[8];
  const float* cb3    = (const float*)d_in[9];
  const float* dW1    = (const float*)d_in[10];
  const float* db1    = (const float*)d_in[11];
  const float* dW2    = (const float*)d_in[12];
  const float* db2    = (const float*)d_in[13];
  const float* dW3    = (const float*)d_in[14];
  const float* db3    = (const float*)d_in[15];
  const float* fW1    = (const float*)d_in[16];
  const float* fb1    = (const float*)d_in[17];
  const float* fW2    = (const float*)d_in[18];
  const float* fb2    = (const float*)d_in[19];
  const float* demb   = (const float*)d_in[20];
  const float* aW1    = (const float*)d_in[21];
  const float* ab1    = (const float*)d_in[22];
  const float* aW2    = (const float*)d_in[23];
  const float* ab2    = (const float*)d_in[24];
  float* out = (float*)d_out;

  char* w = (char*)d_ws;
  int*   cnt2   = (int*)(w + 16);       // [4]
  int*   pstart = (int*)(w + 32);       // [5]
  float* aux    = (float*)(w + 64);     // [4]
  int*   perm   = (int*)(w + 256);                     // [MPAD]
  int*   rowpos = (int*)(w + 67840);                   // [NB]
  bf16*  bufA   = (bf16*)(w + 133376);                 // norm (MPADx1024) then h2 (MPADx512)
  bf16*  bufB   = (bf16*)(w + 34736384);               // h1 (MPADx1024)
  bf16*  cW1t   = (bf16*)(w + 69339392);
  bf16*  cW2t   = (bf16*)(w + 70387968);
  bf16*  cW3t   = (bf16*)(w + 70650112);
  bf16*  dW1t   = (bf16*)(w + 70715648);
  bf16*  dW2t   = (bf16*)(w + 74909952);
  bf16*  dW3t   = (bf16*)(w + 75958528);
  bf16*  fW1t   = (bf16*)(w + 76220672);               // 64x128 bf16; end 76237056

  k_histscan_aux<<<1, 1024, 0, stream>>>(dom, pstart, cnt2, perm, aux,
                                         demb, aW1, ab1, aW2, ab2);
  k_assign<<<64, 256, 0, stream>>>(dom, pstart, cnt2, perm, rowpos);
  k_ln<<<4096, 256, 0, stream>>>(x, dom, rowpos, pn_w, pn_b, bufA);
  k_wt_all<<<842, 256, 0, stream>>>(cW1, cW2, cW3, dW1, dW2, dW3, fW1,
                                    cW1t, cW2t, cW3t, dW1t, dW2t, dW3t, fW1t);

  // L1: norm(bufA) -> h1(bufB) : K=1024, Nh=512, relu, 8 col tiles
  k_gemm<<<1056, 256, 0, stream>>>(bufA, 1024, 0, 0, cW1t, dW1t, cb1, db1,
                                   bufB, 512, 1024, 1, pstart, 3);
  // L2: h1(bufB) -> h2(bufA) : K=512, Nh=256, relu, 4 col tiles
  k_gemm<<<528, 256, 0, stream>>>(bufB, 1024, 0, 512, cW2t, dW2t, cb2, db2,
                                  bufA, 256, 512, 1, pstart, 2);
  // L3 + head fused: h2(bufA) -> out
  k_gemm3<<<264, 256, 0, stream>>>(bufA, cW3t, dW3t, cb3, db3, fW1t,
                                   fb1, fW2, fb2, perm, pstart, aux, out);
}

// Round 4
// 254.426 us; speedup vs baseline: 1.3718x; 1.0516x over previous
//
#include <hip/hip_runtime.h>
#include <hip/hip_bf16.h>
#include <stdint.h>

#define NB   16384
#define DIN  1024
#define MPAD 16896   /* 16384 + 4*128 : per-domain segments padded to 128 */

typedef __bf16 bf16;
typedef __bf16 v8bf __attribute__((ext_vector_type(8)));
typedef float  v4f  __attribute__((ext_vector_type(4)));
typedef unsigned char u8;

typedef __attribute__((address_space(1))) void* as1_ptr;
typedef __attribute__((address_space(3))) void* as3_ptr;

__device__ __forceinline__ void gl_lds16(const void* g, void* l) {
  __builtin_amdgcn_global_load_lds((as1_ptr)(g), (as3_ptr)(l), 16, 0, 0);
}

__device__ __forceinline__ unsigned short bfbits(float f) {
  bf16 h = (bf16)f;
  return __builtin_bit_cast(unsigned short, h);
}

// pack 2 floats -> 2 fp8 e4m3 bytes (byte0=a, byte1=b)
__device__ __forceinline__ unsigned short pk8(float a, float b) {
  int u = __builtin_amdgcn_cvt_pk_fp8_f32(a, b, 0, false);
  return (unsigned short)(u & 0xffff);
}

// ------------------------------------------------ sort: hist+scan+aux+assign (1 block)
__global__ __launch_bounds__(1024) void k_sort(
    const int* __restrict__ dom, int* __restrict__ pstart_g,
    int* __restrict__ perm, int* __restrict__ rowpos, float* __restrict__ aux,
    const float* __restrict__ dom_emb, const float* __restrict__ aW1,
    const float* __restrict__ ab1, const float* __restrict__ aW2,
    const float* __restrict__ ab2) {
  __shared__ int sc0[1024], sc1[1024], sc2[1024], sc3[1024];
  const int tid = threadIdx.x;
  int dv[16];
  int c0 = 0, c1 = 0, c2 = 0, c3 = 0;
#pragma unroll
  for (int it = 0; it < 16; it++) {
    int d = dom[it * 1024 + tid];
    dv[it] = d;
    c0 += (d == 0); c1 += (d == 1); c2 += (d == 2); c3 += (d == 3);
  }
  sc0[tid] = c0; sc1[tid] = c1; sc2[tid] = c2; sc3[tid] = c3;
  for (int j = tid; j < MPAD; j += 1024) perm[j] = -1;
  __syncthreads();
  for (int off = 1; off < 1024; off <<= 1) {
    int v0 = (tid >= off) ? sc0[tid - off] : 0;
    int v1 = (tid >= off) ? sc1[tid - off] : 0;
    int v2 = (tid >= off) ? sc2[tid - off] : 0;
    int v3 = (tid >= off) ? sc3[tid - off] : 0;
    __syncthreads();
    sc0[tid] += v0; sc1[tid] += v1; sc2[tid] += v2; sc3[tid] += v3;
    __syncthreads();
  }
  const int t0 = sc0[1023], t1 = sc1[1023], t2 = sc2[1023];
  const int s1 = (t0 + 127) & ~127;
  const int s2 = s1 + ((t1 + 127) & ~127);
  const int s3 = s2 + ((t2 + 127) & ~127);
  int b0 = 0 + sc0[tid] - c0;
  int b1 = s1 + sc1[tid] - c1;
  int b2 = s2 + sc2[tid] - c2;
  int b3 = s3 + sc3[tid] - c3;
#pragma unroll
  for (int it = 0; it < 16; it++) {
    int i = it * 1024 + tid;
    int d = dv[it];
    int pos = (d == 0) ? b0++ : ((d == 1) ? b1++ : ((d == 2) ? b2++ : b3++));
    perm[pos] = i;
    rowpos[i] = pos;
  }
  if (tid == 0) {
    int t3 = sc3[1023];
    pstart_g[0] = 0; pstart_g[1] = s1; pstart_g[2] = s2; pstart_g[3] = s3;
    pstart_g[4] = s3 + ((t3 + 127) & ~127);
  }
  if (tid < 4) {
    float a = ab2[0];
    for (int j = 0; j < 32; j++) {
      float s = ab1[j];
      for (int i = 0; i < 16; i++) s += dom_emb[tid * 16 + i] * aW1[i * 32 + j];
      a += fmaxf(s, 0.f) * aW2[j];
    }
    aux[tid] = a;
  }
}

// ------------------------------------------------ layernorm -> sorted fp8
__global__ __launch_bounds__(256) void k_ln(const float* __restrict__ x,
                                            const int* __restrict__ dom,
                                            const int* __restrict__ rowpos,
                                            const float* __restrict__ pn_w,
                                            const float* __restrict__ pn_b,
                                            u8* __restrict__ norm) {
  int wv = threadIdx.x >> 6, lane = threadIdx.x & 63;
  int r = blockIdx.x * 4 + wv;
  const float* xr = x + (size_t)r * DIN;
  float4 v[4];
#pragma unroll
  for (int g = 0; g < 4; g++) v[g] = *(const float4*)(xr + g * 256 + lane * 4);
  float s = 0.f;
#pragma unroll
  for (int g = 0; g < 4; g++) s += v[g].x + v[g].y + v[g].z + v[g].w;
#pragma unroll
  for (int o = 32; o; o >>= 1) s += __shfl_xor(s, o, 64);
  float mean = s * (1.f / 1024.f);
  float q = 0.f;
#pragma unroll
  for (int g = 0; g < 4; g++) {
    float a = v[g].x - mean, b = v[g].y - mean, c = v[g].z - mean, e = v[g].w - mean;
    q += a * a + b * b + c * c + e * e;
  }
#pragma unroll
  for (int o = 32; o; o >>= 1) q += __shfl_xor(q, o, 64);
  float rstd = rsqrtf(q * (1.f / 1024.f) + 1e-5f);
  int d = dom[r];
  int pos = rowpos[r];
  const float* pw = pn_w + (size_t)d * DIN;
  const float* pb = pn_b + (size_t)d * DIN;
  u8* orow = norm + (size_t)pos * DIN;
#pragma unroll
  for (int g = 0; g < 4; g++) {
    float4 w4 = *(const float4*)(pw + g * 256 + lane * 4);
    float4 b4 = *(const float4*)(pb + g * 256 + lane * 4);
    float f0 = (v[g].x - mean) * rstd * w4.x + b4.x;
    float f1 = (v[g].y - mean) * rstd * w4.y + b4.y;
    float f2 = (v[g].z - mean) * rstd * w4.z + b4.z;
    float f3 = (v[g].w - mean) * rstd * w4.w + b4.w;
    int u = __builtin_amdgcn_cvt_pk_fp8_f32(f0, f1, 0, false);
    u = __builtin_amdgcn_cvt_pk_fp8_f32(f2, f3, u, true);
    *(unsigned int*)(orow + g * 256 + lane * 4) = (unsigned int)u;
  }
}

// ------------------------------------------------ weight transpose/convert
// 15 fp8 matrices (KxN fp32 -> NxK fp8, x16 scale) + fW1 (bf16), 842 blocks
__global__ __launch_bounds__(256) void k_wt_all(
    const float* __restrict__ cW1, const float* __restrict__ cW2,
    const float* __restrict__ cW3, const float* __restrict__ dW1,
    const float* __restrict__ dW2, const float* __restrict__ dW3,
    const float* __restrict__ fW1,
    u8* __restrict__ cW1t, u8* __restrict__ cW2t, u8* __restrict__ cW3t,
    u8* __restrict__ dW1t, u8* __restrict__ dW2t, u8* __restrict__ dW3t,
    bf16* __restrict__ fW1t) {
  __shared__ float t[64 * 65];
  int bid = blockIdx.x;
  const float* src; u8* dst; int K, N, tile; bool isf = false;
  if (bid < 640) {
    K = 1024; N = 512; int m = bid >> 7; tile = bid & 127;
    src = m == 0 ? cW1 : dW1 + (size_t)(m - 1) * 524288;
    dst = m == 0 ? cW1t : dW1t + (size_t)(m - 1) * 524288;
  } else if (bid < 800) {
    K = 512; N = 256; int m = (bid - 640) >> 5; tile = (bid - 640) & 31;
    src = m == 0 ? cW2 : dW2 + (size_t)(m - 1) * 131072;
    dst = m == 0 ? cW2t : dW2t + (size_t)(m - 1) * 131072;
  } else if (bid < 840) {
    K = 256; N = 128; int m = (bid - 800) >> 3; tile = (bid - 800) & 7;
    src = m == 0 ? cW3 : dW3 + (size_t)(m - 1) * 32768;
    dst = m == 0 ? cW3t : dW3t + (size_t)(m - 1) * 32768;
  } else {
    K = 128; N = 64; tile = bid - 840; src = fW1; dst = nullptr; isf = true;
  }
  int ntn = N >> 6;
  int k0 = (tile / ntn) << 6, n0 = (tile % ntn) << 6;
  int tid = threadIdx.x;
  int r = tid >> 2, c4 = (tid & 3) << 4;
#pragma unroll
  for (int j4 = 0; j4 < 4; j4++) {
    float4 v = *(const float4*)(src + (size_t)(k0 + r) * N + n0 + c4 + j4 * 4);
    t[r * 65 + c4 + j4 * 4 + 0] = v.x;
    t[r * 65 + c4 + j4 * 4 + 1] = v.y;
    t[r * 65 + c4 + j4 * 4 + 2] = v.z;
    t[r * 65 + c4 + j4 * 4 + 3] = v.w;
  }
  __syncthreads();
  int n = tid >> 2, kc = (tid & 3) << 4;
  if (!isf) {
#pragma unroll
    for (int j4 = 0; j4 < 4; j4++) {
      float v0 = t[(kc + j4 * 4 + 0) * 65 + n] * 16.f;
      float v1 = t[(kc + j4 * 4 + 1) * 65 + n] * 16.f;
      float v2 = t[(kc + j4 * 4 + 2) * 65 + n] * 16.f;
      float v3 = t[(kc + j4 * 4 + 3) * 65 + n] * 16.f;
      int u = __builtin_amdgcn_cvt_pk_fp8_f32(v0, v1, 0, false);
      u = __builtin_amdgcn_cvt_pk_fp8_f32(v2, v3, u, true);
      *(unsigned int*)(dst + (size_t)(n0 + n) * K + k0 + kc + j4 * 4) = (unsigned int)u;
    }
  } else {
#pragma unroll
    for (int j4 = 0; j4 < 4; j4++) {
      ushort4 o;
      o.x = bfbits(t[(kc + j4 * 4 + 0) * 65 + n]);
      o.y = bfbits(t[(kc + j4 * 4 + 1) * 65 + n]);
      o.z = bfbits(t[(kc + j4 * 4 + 2) * 65 + n]);
      o.w = bfbits(t[(kc + j4 * 4 + 3) * 65 + n]);
      *(ushort4*)(fW1t + (size_t)(n0 + n) * K + k0 + kc + j4 * 4) = o;
    }
  }
}

// ------------------------------------------------ fused center|domain fp8 GEMM (L1, L2)
// weights pre-scaled x16 -> acc * 1/16. XCD-swizzled 1D grid.
__global__ __launch_bounds__(256) void k_gemm(const u8* __restrict__ A, int lda,
                                              int aoffc, int aoffd,
                                              const u8* __restrict__ cWt,
                                              const u8* __restrict__ dWt,
                                              const float* __restrict__ cb,
                                              const float* __restrict__ db,
                                              u8* __restrict__ C, int Nh, int Kd,
                                              int relu, const int* __restrict__ pstart,
                                              int lognct) {
  __shared__ __align__(16) u8 Al[128 * 64];   // 8 KB
  __shared__ __align__(16) u8 Bl[128 * 64];   // 8 KB
  const int tid = threadIdx.x;
  const int wv = tid >> 6, lane = tid & 63;
  const int nct = 1 << lognct;
  const int T1 = nct << 7;
  int l = blockIdx.x, rt, ct;
  if (l < T1) {
    int t = l >> 3;
    ct = t & (nct - 1);
    rt = ((t >> lognct) << 3) | (l & 7);
  } else {
    int l2 = l - T1;
    rt = 128 + (l2 >> lognct);
    ct = l2 & (nct - 1);
  }
  const int row0 = rt * 128;
  int d = 0;
  if (row0 >= pstart[1]) d = 1;
  if (row0 >= pstart[2]) d = 2;
  if (row0 >= pstart[3]) d = 3;
  const int n0 = ct * 128;
  const bool isd = (n0 >= Nh);
  const u8* Wt = isd ? dWt + ((size_t)d * Nh + (n0 - Nh)) * Kd : cWt + (size_t)n0 * Kd;
  const float* bias = isd ? db + d * Nh + (n0 - Nh) : cb + n0;
  const int aoff = isd ? aoffd : aoffc;
  const u8* Ab = A + (size_t)row0 * lda + aoff;

  v4f acc[4][4];
#pragma unroll
  for (int i = 0; i < 4; i++)
#pragma unroll
    for (int j = 0; j < 4; j++) acc[i][j] = v4f{0.f, 0.f, 0.f, 0.f};

  const int wm = (wv >> 1) * 64, wn = (wv & 1) * 64;
  const int mrow = lane & 15, quad = lane >> 4;
  const int lrow = lane >> 2;   // loader: 16 rows per instr
  const int lchk = lane & 3;    // loader: 4 chunks of 16B per row
  const int ldc = 2 * Nh;

  for (int kt = 0; kt < Kd; kt += 64) {
#pragma unroll
    for (int p = 0; p < 2; p++) {
      int rbase = wv * 32 + p * 16;
      int r = rbase + lrow;
      int jg = lchk ^ (r & 3);   // XOR swizzle over 4 x 16B chunks
      gl_lds16(Ab + (size_t)r * lda + kt + jg * 16, &Al[rbase * 64]);
      gl_lds16(Wt + (size_t)r * Kd + kt + jg * 16, &Bl[rbase * 64]);
    }
    __syncthreads();
#pragma unroll
    for (int s = 0; s < 2; s++) {
      long af[4], bfr[4];
#pragma unroll
      for (int mi = 0; mi < 4; mi++) {
        int m = wm + mi * 16 + mrow;
        int jc = s * 2 + (quad >> 1);
        int js = jc ^ (m & 3);
        af[mi] = *(const long*)&Al[m * 64 + js * 16 + (quad & 1) * 8];
      }
#pragma unroll
      for (int ni = 0; ni < 4; ni++) {
        int n = wn + ni * 16 + mrow;
        int jc = s * 2 + (quad >> 1);
        int js = jc ^ (n & 3);
        bfr[ni] = *(const long*)&Bl[n * 64 + js * 16 + (quad & 1) * 8];
      }
#pragma unroll
      for (int mi = 0; mi < 4; mi++)
#pragma unroll
        for (int ni = 0; ni < 4; ni++)
          acc[mi][ni] =
              __builtin_amdgcn_mfma_f32_16x16x32_fp8_fp8(af[mi], bfr[ni], acc[mi][ni], 0, 0, 0);
    }
    __syncthreads();
  }

  float bv[4];
#pragma unroll
  for (int ni = 0; ni < 4; ni++) bv[ni] = bias[wn + ni * 16 + mrow];
#pragma unroll
  for (int mi = 0; mi < 4; mi++) {
    int growb = row0 + wm + mi * 16 + quad * 4;
#pragma unroll
    for (int ni = 0; ni < 4; ni++) {
      int gcol = n0 + wn + ni * 16 + mrow;
#pragma unroll
      for (int r2 = 0; r2 < 4; r2++) {
        float v = acc[mi][ni][r2] * 0.0625f + bv[ni];
        if (relu) v = fmaxf(v, 0.f);
        float g = __shfl_xor(v, 1, 64);
        if (!(mrow & 1))
          *(unsigned short*)(C + (size_t)(growb + r2) * ldc + gcol) = pk8(v, g);
      }
    }
  }
}

// ------------------------------------------------ L3 fp8 GEMM + bf16 MFMA head
__global__ __launch_bounds__(256) void k_gemm3(const u8* __restrict__ A,
                                               const u8* __restrict__ cW3t,
                                               const u8* __restrict__ dW3t,
                                               const float* __restrict__ cb3,
                                               const float* __restrict__ db3,
                                               const bf16* __restrict__ fW1t,
                                               const float* __restrict__ fb1,
                                               const float* __restrict__ fW2,
                                               const float* __restrict__ fb2,
                                               const int* __restrict__ perm,
                                               const int* __restrict__ pstart,
                                               const float* __restrict__ aux,
                                               float* __restrict__ out) {
  __shared__ __align__(16) u8 Al[64 * 64];         // 4 KB
  __shared__ __align__(16) u8 Bl[128 * 64];        // 8 KB
  __shared__ __align__(16) bf16 fusedL[64 * 128];  // 16 KB, XOR-swizzled 8-elt chunks
  __shared__ __align__(16) bf16 fwB[64 * 128];     // 16 KB, XOR-swizzled 8-elt chunks
  const int tid = threadIdx.x, wv = tid >> 6, lane = tid & 63;
  const int row0 = blockIdx.x * 64;
  const int d = (row0 >= pstart[1]) + (row0 >= pstart[2]) + (row0 >= pstart[3]);
  const u8* Ab = A + (size_t)row0 * 512;
  const int mrow = lane & 15, quad = lane >> 4;
  const int lrow = lane >> 2, lchk = lane & 3;
  const int wm = (wv >> 1) * 32, wn = (wv & 1) * 64;

  // stage fW1t (64 rows x 128 bf16) swizzled: chunk c at row holds g=(c&8)|((c^row)&7)
  {
    int c = lane & 15, rsub = lane >> 4;
#pragma unroll
    for (int p = 0; p < 4; p++) {
      int rbase = wv * 16 + p * 4;
      int row = rbase + rsub;
      int g = (c & 8) | ((c ^ row) & 7);
      gl_lds16(fW1t + row * 128 + g * 8, &fwB[rbase * 128]);
    }
  }

  v4f accC[2][4], accD[2][4];
#pragma unroll
  for (int i = 0; i < 2; i++)
#pragma unroll
    for (int j = 0; j < 4; j++) { accC[i][j] = v4f{0.f,0.f,0.f,0.f}; accD[i][j] = v4f{0.f,0.f,0.f,0.f}; }

#pragma unroll
  for (int ph = 0; ph < 2; ph++) {
    const u8* Wt = ph ? dW3t + (size_t)d * 32768 : cW3t;
    const int aoff = ph * 256;
    for (int kt = 0; kt < 256; kt += 64) {
      {
        int rbase = wv * 16;
        int r = rbase + lrow;
        int jg = lchk ^ (r & 3);
        gl_lds16(Ab + (size_t)r * 512 + aoff + kt + jg * 16, &Al[rbase * 64]);
      }
#pragma unroll
      for (int p = 0; p < 2; p++) {
        int rbase = wv * 32 + p * 16;
        int r = rbase + lrow;
        int jg = lchk ^ (r & 3);
        gl_lds16(Wt + (size_t)r * 256 + kt + jg * 16, &Bl[rbase * 64]);
      }
      __syncthreads();
#pragma unroll
      for (int s = 0; s < 2; s++) {
        long af[2], bfr[4];
#pragma unroll
        for (int mi = 0; mi < 2; mi++) {
          int m = wm + mi * 16 + mrow;
          int jc = s * 2 + (quad >> 1);
          int js = jc ^ (m & 3);
          af[mi] = *(const long*)&Al[m * 64 + js * 16 + (quad & 1) * 8];
        }
#pragma unroll
        for (int ni = 0; ni < 4; ni++) {
          int n = wn + ni * 16 + mrow;
          int jc = s * 2 + (quad >> 1);
          int js = jc ^ (n & 3);
          bfr[ni] = *(const long*)&Bl[n * 64 + js * 16 + (quad & 1) * 8];
        }
        if (ph == 0) {
#pragma unroll
          for (int mi = 0; mi < 2; mi++)
#pragma unroll
            for (int ni = 0; ni < 4; ni++)
              accC[mi][ni] = __builtin_amdgcn_mfma_f32_16x16x32_fp8_fp8(af[mi], bfr[ni], accC[mi][ni], 0, 0, 0);
        } else {
#pragma unroll
          for (int mi = 0; mi < 2; mi++)
#pragma unroll
            for (int ni = 0; ni < 4; ni++)
              accD[mi][ni] = __builtin_amdgcn_mfma_f32_16x16x32_fp8_fp8(af[mi], bfr[ni], accD[mi][ni], 0, 0, 0);
        }
      }
      __syncthreads();
    }
  }

  // epilogue: fused = (hC + cb3) * tanh(hD + db3), swizzled into fusedL
#pragma unroll
  for (int mi = 0; mi < 2; mi++) {
    int rowb = wm + mi * 16 + quad * 4;
#pragma unroll
    for (int ni = 0; ni < 4; ni++) {
      int col = wn + ni * 16 + mrow;
      float cbv = cb3[col];
      float dbv = db3[d * 128 + col];
      int jc = col >> 3, coff = col & 7;
#pragma unroll
      for (int r2 = 0; r2 < 4; r2++) {
        int rr = rowb + r2;
        float f = (accC[mi][ni][r2] * 0.0625f + cbv) * tanhf(accD[mi][ni][r2] * 0.0625f + dbv);
        int cs = (jc & 8) | ((jc ^ rr) & 7);
        fusedL[rr * 128 + cs * 8 + coff] = (bf16)f;
      }
    }
  }
  __syncthreads();

  // head: wave wv computes rows wv*16..+15, 64 neurons, via bf16 MFMA (K=128)
  float fb1v[4], fW2v[4];
#pragma unroll
  for (int nt = 0; nt < 4; nt++) {
    int col = nt * 16 + mrow;
    fb1v[nt] = fb1[col];
    fW2v[nt] = fW2[col];
  }
  v4f hacc[4];
#pragma unroll
  for (int nt = 0; nt < 4; nt++) hacc[nt] = v4f{0.f, 0.f, 0.f, 0.f};
  const int m = wv * 16 + mrow;
#pragma unroll
  for (int s = 0; s < 4; s++) {
    int j = s * 4 + quad;
    int ca = (j & 8) | ((j ^ m) & 7);
    v8bf af = *(const v8bf*)&fusedL[m * 128 + ca * 8];
#pragma unroll
    for (int nt = 0; nt < 4; nt++) {
      int n = nt * 16 + mrow;
      int cbk = (j & 8) | ((j ^ n) & 7);
      v8bf bfr = *(const v8bf*)&fwB[n * 128 + cbk * 8];
      hacc[nt] = __builtin_amdgcn_mfma_f32_16x16x32_bf16(af, bfr, hacc[nt], 0, 0, 0);
    }
  }
  float ys[4];
#pragma unroll
  for (int r2 = 0; r2 < 4; r2++) {
    float s = 0.f;
#pragma unroll
    for (int nt = 0; nt < 4; nt++) s += fmaxf(hacc[nt][r2] + fb1v[nt], 0.f) * fW2v[nt];
    ys[r2] = s;
  }
#pragma unroll
  for (int o = 1; o < 16; o <<= 1)
#pragma unroll
    for (int r2 = 0; r2 < 4; r2++) ys[r2] += __shfl_xor(ys[r2], o, 64);
  if (mrow == 0) {
    const float addc = fb2[0] + aux[d];
#pragma unroll
    for (int r2 = 0; r2 < 4; r2++) {
      int prow = row0 + wv * 16 + quad * 4 + r2;
      int orig = perm[prow];
      if (orig >= 0) out[orig] = 1.f / (1.f + expf(-(ys[r2] + addc)));
    }
  }
}

// ------------------------------------------------ launch
extern "C" void kernel_launch(void* const* d_in, const int* in_sizes, int n_in,
                              void* d_out, int out_size, void* d_ws, size_t ws_size,
                              hipStream_t stream) {
  (void)in_sizes; (void)n_in; (void)out_size; (void)ws_size;
  const float* x      = (const float*)d_in[0];
  const int*   dom    = (const int*)d_in[1];
  const float* pn_w   = (const float*)d_in[2];
  const float* pn_b   = (const float*)d_in[3];
  const float* cW1    = (const float*)d_in[4];
  const float* cb1    = (const float*)d_in[5];
  const float* cW2    = (const float*)d_in[6];
  const float* cb2    = (const float*)d_in[7];
  const float* cW3    = (const float*)d_in[8];
  const float* cb3    = (const float*)d_in[9];
  const float* dW1    = (const float*)d_in[10];
  const float* db1    = (const float*)d_in[11];
  const float* dW2    = (const float*)d_in[12];
  const float* db2    = (const float*)d_in[13];
  const float* dW3    = (const float*)d_in[14];
  const float* db3    = (const float*)d_in[15];
  const float* fW1    = (const float*)d_in[16];
  const float* fb1    = (const float*)d_in[17];
  const float* fW2    = (const float*)d_in[18];
  const float* fb2    = (const float*)d_in[19];
  const float* demb   = (const float*)d_in[20];
  const float* aW1    = (const float*)d_in[21];
  const float* ab1    = (const float*)d_in[22];
  const float* aW2    = (const float*)d_in[23];
  const float* ab2    = (const float*)d_in[24];
  float* out = (float*)d_out;

  char* w = (char*)d_ws;
  int*   pstart = (int*)(w + 32);       // [5]
  float* aux    = (float*)(w + 64);     // [4]
  int*   perm   = (int*)(w + 256);                     // [MPAD] -> 67840
  int*   rowpos = (int*)(w + 67840);                   // [NB]   -> 133376
  u8*    bufA   = (u8*)(w + 133376);                   // norm MPADx1024 fp8, then h2 MPADx512
  u8*    bufB   = (u8*)(w + 17434880);                 // h1 MPADx1024 fp8
  u8*    cW1t   = (u8*)(w + 34736384);
  u8*    cW2t   = (u8*)(w + 35260672);
  u8*    cW3t   = (u8*)(w + 35391744);
  u8*    dW1t   = (u8*)(w + 35424512);
  u8*    dW2t   = (u8*)(w + 37521664);
  u8*    dW3t   = (u8*)(w + 38045952);
  bf16*  fW1t   = (bf16*)(w + 38177024);               // 64x128 bf16 -> end 38193408

  k_sort<<<1, 1024, 0, stream>>>(dom, pstart, perm, rowpos, aux,
                                 demb, aW1, ab1, aW2, ab2);
  k_ln<<<4096, 256, 0, stream>>>(x, dom, rowpos, pn_w, pn_b, bufA);
  k_wt_all<<<842, 256, 0, stream>>>(cW1, cW2, cW3, dW1, dW2, dW3, fW1,
                                    cW1t, cW2t, cW3t, dW1t, dW2t, dW3t, fW1t);

  // L1: norm(bufA) -> h1(bufB) : K=1024, Nh=512, relu, 8 col tiles
  k_gemm<<<1056, 256, 0, stream>>>(bufA, 1024, 0, 0, cW1t, dW1t, cb1, db1,
                                   bufB, 512, 1024, 1, pstart, 3);
  // L2: h1(bufB) -> h2(bufA) : K=512, Nh=256, relu, 4 col tiles
  k_gemm<<<528, 256, 0, stream>>>(bufB, 1024, 0, 512, cW2t, dW2t, cb2, db2,
                                  bufA, 256, 512, 1, pstart, 2);
  // L3 + head fused: h2(bufA) -> out
  k_gemm3<<<264, 256, 0, stream>>>(bufA, cW3t, dW3t, cb3, db3, fW1t,
                                   fb1, fW2, fb2, perm, pstart, aux, out);
}

// Round 5
// 235.120 us; speedup vs baseline: 1.4845x; 1.0821x over previous
//
#include <hip/hip_runtime.h>
#include <hip/hip_bf16.h>
#include <stdint.h>

#define NB   16384
#define DIN  1024
#define MPAD 16896   /* 16384 + 4*128 : per-domain segments padded to 128 */

typedef __bf16 bf16;
typedef __bf16 v8bf __attribute__((ext_vector_type(8)));
typedef float  v4f  __attribute__((ext_vector_type(4)));
typedef long   v2l  __attribute__((ext_vector_type(2)));
typedef unsigned char u8;

typedef __attribute__((address_space(1))) void* as1_ptr;
typedef __attribute__((address_space(3))) void* as3_ptr;

__device__ __forceinline__ void gl_lds16(const void* g, void* l) {
  __builtin_amdgcn_global_load_lds((as1_ptr)(g), (as3_ptr)(l), 16, 0, 0);
}

__device__ __forceinline__ unsigned short bfbits(float f) {
  bf16 h = (bf16)f;
  return __builtin_bit_cast(unsigned short, h);
}

// pack 2 floats -> 2 fp8 e4m3 bytes (byte0=a, byte1=b)
__device__ __forceinline__ unsigned short pk8(float a, float b) {
  int u = __builtin_amdgcn_cvt_pk_fp8_f32(a, b, 0, false);
  return (unsigned short)(u & 0xffff);
}

// ------------------------------------------------ histogram + scan + aux + perm init
__global__ __launch_bounds__(1024) void k_histscan_aux(
    const int* __restrict__ dom, int* __restrict__ pstart, int* __restrict__ cnt2,
    int* __restrict__ perm, float* __restrict__ aux,
    const float* __restrict__ dom_emb, const float* __restrict__ aW1,
    const float* __restrict__ ab1, const float* __restrict__ aW2,
    const float* __restrict__ ab2) {
  __shared__ int hist[4];
  int tid = threadIdx.x, lane = tid & 63;
  if (tid < 4) hist[tid] = 0;
  if (tid >= 8 && tid < 12) cnt2[tid - 8] = 0;
  for (int j = tid; j < MPAD; j += 1024) perm[j] = -1;
  __syncthreads();
  int c0 = 0, c1 = 0, c2 = 0, c3 = 0;
#pragma unroll
  for (int it = 0; it < 16; it++) {
    int d = dom[it * 1024 + tid];
    c0 += (d == 0); c1 += (d == 1); c2 += (d == 2); c3 += (d == 3);
  }
#pragma unroll
  for (int o = 32; o; o >>= 1) {
    c0 += __shfl_xor(c0, o, 64); c1 += __shfl_xor(c1, o, 64);
    c2 += __shfl_xor(c2, o, 64); c3 += __shfl_xor(c3, o, 64);
  }
  if (lane == 0) {
    atomicAdd(&hist[0], c0); atomicAdd(&hist[1], c1);
    atomicAdd(&hist[2], c2); atomicAdd(&hist[3], c3);
  }
  __syncthreads();
  if (tid == 0) {
    int p = 0;
    for (int d = 0; d < 4; d++) { pstart[d] = p; p += (hist[d] + 127) & ~127; }
    pstart[4] = p;
  }
  if (tid < 4) {
    float a = ab2[0];
    for (int j = 0; j < 32; j++) {
      float s = ab1[j];
      for (int i = 0; i < 16; i++) s += dom_emb[tid * 16 + i] * aW1[i * 32 + j];
      a += fmaxf(s, 0.f) * aW2[j];
    }
    aux[tid] = a;
  }
}

// ------------------------------------------------ assign sorted positions
__global__ void k_assign(const int* __restrict__ dom, const int* __restrict__ pstart,
                         int* __restrict__ cnt2, int* __restrict__ perm,
                         int* __restrict__ rowpos) {
  int i = blockIdx.x * 256 + threadIdx.x;
  int lane = threadIdx.x & 63;
  int d = dom[i];
  unsigned long long ltmask = (1ull << lane) - 1ull;
#pragma unroll
  for (int dd = 0; dd < 4; dd++) {
    unsigned long long m = __ballot(d == dd);
    int c = __popcll(m);
    int base = 0;
    if (lane == 0 && c) base = atomicAdd(&cnt2[dd], c);
    base = __shfl(base, 0, 64);
    if (d == dd) {
      int pos = pstart[dd] + base + __popcll(m & ltmask);
      perm[pos] = i;
      rowpos[i] = pos;
    }
  }
}

// ------------------------------------------------ layernorm -> sorted fp8
__global__ __launch_bounds__(256) void k_ln(const float* __restrict__ x,
                                            const int* __restrict__ dom,
                                            const int* __restrict__ rowpos,
                                            const float* __restrict__ pn_w,
                                            const float* __restrict__ pn_b,
                                            u8* __restrict__ norm) {
  int wv = threadIdx.x >> 6, lane = threadIdx.x & 63;
  int r = blockIdx.x * 4 + wv;
  const float* xr = x + (size_t)r * DIN;
  float4 v[4];
#pragma unroll
  for (int g = 0; g < 4; g++) v[g] = *(const float4*)(xr + g * 256 + lane * 4);
  float s = 0.f;
#pragma unroll
  for (int g = 0; g < 4; g++) s += v[g].x + v[g].y + v[g].z + v[g].w;
#pragma unroll
  for (int o = 32; o; o >>= 1) s += __shfl_xor(s, o, 64);
  float mean = s * (1.f / 1024.f);
  float q = 0.f;
#pragma unroll
  for (int g = 0; g < 4; g++) {
    float a = v[g].x - mean, b = v[g].y - mean, c = v[g].z - mean, e = v[g].w - mean;
    q += a * a + b * b + c * c + e * e;
  }
#pragma unroll
  for (int o = 32; o; o >>= 1) q += __shfl_xor(q, o, 64);
  float rstd = rsqrtf(q * (1.f / 1024.f) + 1e-5f);
  int d = dom[r];
  int pos = rowpos[r];
  const float* pw = pn_w + (size_t)d * DIN;
  const float* pb = pn_b + (size_t)d * DIN;
  u8* orow = norm + (size_t)pos * DIN;
#pragma unroll
  for (int g = 0; g < 4; g++) {
    float4 w4 = *(const float4*)(pw + g * 256 + lane * 4);
    float4 b4 = *(const float4*)(pb + g * 256 + lane * 4);
    float f0 = (v[g].x - mean) * rstd * w4.x + b4.x;
    float f1 = (v[g].y - mean) * rstd * w4.y + b4.y;
    float f2 = (v[g].z - mean) * rstd * w4.z + b4.z;
    float f3 = (v[g].w - mean) * rstd * w4.w + b4.w;
    int u = __builtin_amdgcn_cvt_pk_fp8_f32(f0, f1, 0, false);
    u = __builtin_amdgcn_cvt_pk_fp8_f32(f2, f3, u, true);
    *(unsigned int*)(orow + g * 256 + lane * 4) = (unsigned int)u;
  }
}

// ------------------------------------------------ weight transpose/convert
// 15 fp8 matrices (KxN fp32 -> NxK fp8, x16 scale) + fW1 (bf16), 842 blocks
__global__ __launch_bounds__(256) void k_wt_all(
    const float* __restrict__ cW1, const float* __restrict__ cW2,
    const float* __restrict__ cW3, const float* __restrict__ dW1,
    const float* __restrict__ dW2, const float* __restrict__ dW3,
    const float* __restrict__ fW1,
    u8* __restrict__ cW1t, u8* __restrict__ cW2t, u8* __restrict__ cW3t,
    u8* __restrict__ dW1t, u8* __restrict__ dW2t, u8* __restrict__ dW3t,
    bf16* __restrict__ fW1t) {
  __shared__ float t[64 * 65];
  int bid = blockIdx.x;
  const float* src; u8* dst; int K, N, tile; bool isf = false;
  if (bid < 640) {
    K = 1024; N = 512; int m = bid >> 7; tile = bid & 127;
    src = m == 0 ? cW1 : dW1 + (size_t)(m - 1) * 524288;
    dst = m == 0 ? cW1t : dW1t + (size_t)(m - 1) * 524288;
  } else if (bid < 800) {
    K = 512; N = 256; int m = (bid - 640) >> 5; tile = (bid - 640) & 31;
    src = m == 0 ? cW2 : dW2 + (size_t)(m - 1) * 131072;
    dst = m == 0 ? cW2t : dW2t + (size_t)(m - 1) * 131072;
  } else if (bid < 840) {
    K = 256; N = 128; int m = (bid - 800) >> 3; tile = (bid - 800) & 7;
    src = m == 0 ? cW3 : dW3 + (size_t)(m - 1) * 32768;
    dst = m == 0 ? cW3t : dW3t + (size_t)(m - 1) * 32768;
  } else {
    K = 128; N = 64; tile = bid - 840; src = fW1; dst = nullptr; isf = true;
  }
  int ntn = N >> 6;
  int k0 = (tile / ntn) << 6, n0 = (tile % ntn) << 6;
  int tid = threadIdx.x;
  int r = tid >> 2, c4 = (tid & 3) << 4;
#pragma unroll
  for (int j4 = 0; j4 < 4; j4++) {
    float4 v = *(const float4*)(src + (size_t)(k0 + r) * N + n0 + c4 + j4 * 4);
    t[r * 65 + c4 + j4 * 4 + 0] = v.x;
    t[r * 65 + c4 + j4 * 4 + 1] = v.y;
    t[r * 65 + c4 + j4 * 4 + 2] = v.z;
    t[r * 65 + c4 + j4 * 4 + 3] = v.w;
  }
  __syncthreads();
  int n = tid >> 2, kc = (tid & 3) << 4;
  if (!isf) {
#pragma unroll
    for (int j4 = 0; j4 < 4; j4++) {
      float v0 = t[(kc + j4 * 4 + 0) * 65 + n] * 16.f;
      float v1 = t[(kc + j4 * 4 + 1) * 65 + n] * 16.f;
      float v2 = t[(kc + j4 * 4 + 2) * 65 + n] * 16.f;
      float v3 = t[(kc + j4 * 4 + 3) * 65 + n] * 16.f;
      int u = __builtin_amdgcn_cvt_pk_fp8_f32(v0, v1, 0, false);
      u = __builtin_amdgcn_cvt_pk_fp8_f32(v2, v3, u, true);
      *(unsigned int*)(dst + (size_t)(n0 + n) * K + k0 + kc + j4 * 4) = (unsigned int)u;
    }
  } else {
#pragma unroll
    for (int j4 = 0; j4 < 4; j4++) {
      ushort4 o;
      o.x = bfbits(t[(kc + j4 * 4 + 0) * 65 + n]);
      o.y = bfbits(t[(kc + j4 * 4 + 1) * 65 + n]);
      o.z = bfbits(t[(kc + j4 * 4 + 2) * 65 + n]);
      o.w = bfbits(t[(kc + j4 * 4 + 3) * 65 + n]);
      *(ushort4*)(fW1t + (size_t)(n0 + n) * K + k0 + kc + j4 * 4) = o;
    }
  }
}

// ------------------------------------------------ fused center|domain fp8 GEMM (L1, L2)
// M-tile 64, N-tile 128, BK 128. b128 LDS reads via K-permutation (K is a
// reduction dim: MFMA call pair sp uses global K [sp*64, sp*64+64), lane quad q
// takes bytes [q*16+s*8) — identical perm on A and B => correct).
// LDS slot c of row r holds global 16B chunk c^(r&7)  (xor swizzle, bank-free).
__global__ __launch_bounds__(256) void k_gemm(const u8* __restrict__ A, int lda,
                                              int aoffc, int aoffd,
                                              const u8* __restrict__ cWt,
                                              const u8* __restrict__ dWt,
                                              const float* __restrict__ cb,
                                              const float* __restrict__ db,
                                              u8* __restrict__ C, int Nh, int Kd,
                                              int relu, const int* __restrict__ pstart,
                                              int lognct) {
  __shared__ __align__(16) u8 Al[64 * 128];    // 8 KB
  __shared__ __align__(16) u8 Bl[128 * 128];   // 16 KB
  const int tid = threadIdx.x;
  const int wv = tid >> 6, lane = tid & 63;
  const int nct = 1 << lognct;
  // XCD swizzle: col-tiles of one row-tile share l&7 -> same XCD L2.
  int l = blockIdx.x;
  int t = l >> 3;
  int ct = t & (nct - 1);
  int rt = ((t >> lognct) << 3) | (l & 7);   // 264 row-tiles, 264%8==0
  const int row0 = rt * 64;
  const int d = (row0 >= pstart[1]) + (row0 >= pstart[2]) + (row0 >= pstart[3]);
  const int n0 = ct * 128;
  const bool isd = (n0 >= Nh);
  const u8* Wt = isd ? dWt + ((size_t)d * Nh + (n0 - Nh)) * Kd : cWt + (size_t)n0 * Kd;
  const float* bias = isd ? db + d * Nh + (n0 - Nh) : cb + n0;
  const int aoff = isd ? aoffd : aoffc;
  const u8* Ab = A + (size_t)row0 * lda + aoff;

  v4f acc[2][4];
#pragma unroll
  for (int i = 0; i < 2; i++)
#pragma unroll
    for (int j = 0; j < 4; j++) acc[i][j] = v4f{0.f, 0.f, 0.f, 0.f};

  const int wm = (wv >> 1) * 32, wn = (wv & 1) * 64;
  const int mrow = lane & 15, quad = lane >> 4;
  const int lrow = lane >> 3;   // loader: 8 rows per instr
  const int lchk = lane & 7;    // loader: 8 chunks of 16B per row
  const int ldc = 2 * Nh;

  for (int kt = 0; kt < Kd; kt += 128) {
#pragma unroll
    for (int p = 0; p < 2; p++) {          // A: wave rows [wv*16, +16)
      int rbase = wv * 16 + p * 8;
      int r = rbase + lrow;
      int jg = lchk ^ (r & 7);
      gl_lds16(Ab + (size_t)r * lda + kt + jg * 16, &Al[rbase * 128]);
    }
#pragma unroll
    for (int p = 0; p < 4; p++) {          // B: wave rows [wv*32, +32)
      int rbase = wv * 32 + p * 8;
      int r = rbase + lrow;
      int jg = lchk ^ (r & 7);
      gl_lds16(Wt + (size_t)r * Kd + kt + jg * 16, &Bl[rbase * 128]);
    }
    __syncthreads();
#pragma unroll
    for (int sp = 0; sp < 2; sp++) {
      v2l af[2], bfr[4];
#pragma unroll
      for (int mi = 0; mi < 2; mi++) {
        int m = wm + mi * 16 + mrow;
        int c = (sp * 4 + quad) ^ (m & 7);
        af[mi] = *(const v2l*)&Al[m * 128 + c * 16];
      }
#pragma unroll
      for (int ni = 0; ni < 4; ni++) {
        int n = wn + ni * 16 + mrow;
        int c = (sp * 4 + quad) ^ (n & 7);
        bfr[ni] = *(const v2l*)&Bl[n * 128 + c * 16];
      }
#pragma unroll
      for (int mi = 0; mi < 2; mi++)
#pragma unroll
        for (int ni = 0; ni < 4; ni++)
          acc[mi][ni] =
              __builtin_amdgcn_mfma_f32_16x16x32_fp8_fp8(af[mi].x, bfr[ni].x, acc[mi][ni], 0, 0, 0);
#pragma unroll
      for (int mi = 0; mi < 2; mi++)
#pragma unroll
        for (int ni = 0; ni < 4; ni++)
          acc[mi][ni] =
              __builtin_amdgcn_mfma_f32_16x16x32_fp8_fp8(af[mi].y, bfr[ni].y, acc[mi][ni], 0, 0, 0);
    }
    __syncthreads();
  }

  float bv[4];
#pragma unroll
  for (int ni = 0; ni < 4; ni++) bv[ni] = bias[wn + ni * 16 + mrow];
#pragma unroll
  for (int mi = 0; mi < 2; mi++) {
    int growb = row0 + wm + mi * 16 + quad * 4;
#pragma unroll
    for (int ni = 0; ni < 4; ni++) {
      int gcol = n0 + wn + ni * 16 + mrow;
#pragma unroll
      for (int r2 = 0; r2 < 4; r2++) {
        float v = acc[mi][ni][r2] * 0.0625f + bv[ni];
        if (relu) v = fmaxf(v, 0.f);
        float g = __shfl_xor(v, 1, 64);
        if (!(mrow & 1))
          *(unsigned short*)(C + (size_t)(growb + r2) * ldc + gcol) = pk8(v, g);
      }
    }
  }
}

// ------------------------------------------------ L3 fp8 GEMM + bf16 MFMA head
__global__ __launch_bounds__(256) void k_gemm3(const u8* __restrict__ A,
                                               const u8* __restrict__ cW3t,
                                               const u8* __restrict__ dW3t,
                                               const float* __restrict__ cb3,
                                               const float* __restrict__ db3,
                                               const bf16* __restrict__ fW1t,
                                               const float* __restrict__ fb1,
                                               const float* __restrict__ fW2,
                                               const float* __restrict__ fb2,
                                               const int* __restrict__ perm,
                                               const int* __restrict__ pstart,
                                               const float* __restrict__ aux,
                                               float* __restrict__ out) {
  __shared__ __align__(16) u8 Al[64 * 128];        // 8 KB
  __shared__ __align__(16) u8 Bl[128 * 128];       // 16 KB
  __shared__ __align__(16) bf16 fusedL[64 * 128];  // 16 KB, XOR-swizzled 8-elt chunks
  __shared__ __align__(16) bf16 fwB[64 * 128];     // 16 KB, XOR-swizzled 8-elt chunks
  const int tid = threadIdx.x, wv = tid >> 6, lane = tid & 63;
  const int row0 = blockIdx.x * 64;
  const int d = (row0 >= pstart[1]) + (row0 >= pstart[2]) + (row0 >= pstart[3]);
  const u8* Ab = A + (size_t)row0 * 512;
  const int mrow = lane & 15, quad = lane >> 4;
  const int lrow = lane >> 3, lchk = lane & 7;
  const int wm = (wv >> 1) * 32, wn = (wv & 1) * 64;

  // stage fW1t (64 rows x 128 bf16) swizzled: chunk c at row holds g=(c&8)|((c^row)&7)
  {
    int c = lane & 15, rsub = lane >> 4;
#pragma unroll
    for (int p = 0; p < 4; p++) {
      int rbase = wv * 16 + p * 4;
      int row = rbase + rsub;
      int g = (c & 8) | ((c ^ row) & 7);
      gl_lds16(fW1t + row * 128 + g * 8, &fwB[rbase * 128]);
    }
  }

  v4f accC[2][4], accD[2][4];
#pragma unroll
  for (int i = 0; i < 2; i++)
#pragma unroll
    for (int j = 0; j < 4; j++) { accC[i][j] = v4f{0.f,0.f,0.f,0.f}; accD[i][j] = v4f{0.f,0.f,0.f,0.f}; }

#pragma unroll
  for (int ph = 0; ph < 2; ph++) {
    const u8* Wt = ph ? dW3t + (size_t)d * 32768 : cW3t;
    const int aoff = ph * 256;
    for (int kt = 0; kt < 256; kt += 128) {
#pragma unroll
      for (int p = 0; p < 2; p++) {        // A: 64 rows
        int rbase = wv * 16 + p * 8;
        int r = rbase + lrow;
        int jg = lchk ^ (r & 7);
        gl_lds16(Ab + (size_t)r * 512 + aoff + kt + jg * 16, &Al[rbase * 128]);
      }
#pragma unroll
      for (int p = 0; p < 4; p++) {        // B: 128 rows
        int rbase = wv * 32 + p * 8;
        int r = rbase + lrow;
        int jg = lchk ^ (r & 7);
        gl_lds16(Wt + (size_t)r * 256 + kt + jg * 16, &Bl[rbase * 128]);
      }
      __syncthreads();
#pragma unroll
      for (int sp = 0; sp < 2; sp++) {
        v2l af[2], bfr[4];
#pragma unroll
        for (int mi = 0; mi < 2; mi++) {
          int m = wm + mi * 16 + mrow;
          int c = (sp * 4 + quad) ^ (m & 7);
          af[mi] = *(const v2l*)&Al[m * 128 + c * 16];
        }
#pragma unroll
        for (int ni = 0; ni < 4; ni++) {
          int n = wn + ni * 16 + mrow;
          int c = (sp * 4 + quad) ^ (n & 7);
          bfr[ni] = *(const v2l*)&Bl[n * 128 + c * 16];
        }
        if (ph == 0) {
#pragma unroll
          for (int mi = 0; mi < 2; mi++)
#pragma unroll
            for (int ni = 0; ni < 4; ni++) {
              accC[mi][ni] = __builtin_amdgcn_mfma_f32_16x16x32_fp8_fp8(af[mi].x, bfr[ni].x, accC[mi][ni], 0, 0, 0);
              accC[mi][ni] = __builtin_amdgcn_mfma_f32_16x16x32_fp8_fp8(af[mi].y, bfr[ni].y, accC[mi][ni], 0, 0, 0);
            }
        } else {
#pragma unroll
          for (int mi = 0; mi < 2; mi++)
#pragma unroll
            for (int ni = 0; ni < 4; ni++) {
              accD[mi][ni] = __builtin_amdgcn_mfma_f32_16x16x32_fp8_fp8(af[mi].x, bfr[ni].x, accD[mi][ni], 0, 0, 0);
              accD[mi][ni] = __builtin_amdgcn_mfma_f32_16x16x32_fp8_fp8(af[mi].y, bfr[ni].y, accD[mi][ni], 0, 0, 0);
            }
        }
      }
      __syncthreads();
    }
  }

  // epilogue: fused = (hC + cb3) * tanh(hD + db3), swizzled into fusedL
#pragma unroll
  for (int mi = 0; mi < 2; mi++) {
    int rowb = wm + mi * 16 + quad * 4;
#pragma unroll
    for (int ni = 0; ni < 4; ni++) {
      int col = wn + ni * 16 + mrow;
      float cbv = cb3[col];
      float dbv = db3[d * 128 + col];
      int jc = col >> 3, coff = col & 7;
#pragma unroll
      for (int r2 = 0; r2 < 4; r2++) {
        int rr = rowb + r2;
        float f = (accC[mi][ni][r2] * 0.0625f + cbv) * tanhf(accD[mi][ni][r2] * 0.0625f + dbv);
        int cs = (jc & 8) | ((jc ^ rr) & 7);
        fusedL[rr * 128 + cs * 8 + coff] = (bf16)f;
      }
    }
  }
  __syncthreads();

  // head: wave wv computes rows wv*16..+15, 64 neurons, via bf16 MFMA (K=128)
  float fb1v[4], fW2v[4];
#pragma unroll
  for (int nt = 0; nt < 4; nt++) {
    int col = nt * 16 + mrow;
    fb1v[nt] = fb1[col];
    fW2v[nt] = fW2[col];
  }
  v4f hacc[4];
#pragma unroll
  for (int nt = 0; nt < 4; nt++) hacc[nt] = v4f{0.f, 0.f, 0.f, 0.f};
  const int m = wv * 16 + mrow;
#pragma unroll
  for (int s = 0; s < 4; s++) {
    int j = s * 4 + quad;
    int ca = (j & 8) | ((j ^ m) & 7);
    v8bf af = *(const v8bf*)&fusedL[m * 128 + ca * 8];
#pragma unroll
    for (int nt = 0; nt < 4; nt++) {
      int n = nt * 16 + mrow;
      int cbk = (j & 8) | ((j ^ n) & 7);
      v8bf bfr = *(const v8bf*)&fwB[n * 128 + cbk * 8];
      hacc[nt] = __builtin_amdgcn_mfma_f32_16x16x32_bf16(af, bfr, hacc[nt], 0, 0, 0);
    }
  }
  float ys[4];
#pragma unroll
  for (int r2 = 0; r2 < 4; r2++) {
    float s = 0.f;
#pragma unroll
    for (int nt = 0; nt < 4; nt++) s += fmaxf(hacc[nt][r2] + fb1v[nt], 0.f) * fW2v[nt];
    ys[r2] = s;
  }
#pragma unroll
  for (int o = 1; o < 16; o <<= 1)
#pragma unroll
    for (int r2 = 0; r2 < 4; r2++) ys[r2] += __shfl_xor(ys[r2], o, 64);
  if (mrow == 0) {
    const float addc = fb2[0] + aux[d];
#pragma unroll
    for (int r2 = 0; r2 < 4; r2++) {
      int prow = row0 + wv * 16 + quad * 4 + r2;
      int orig = perm[prow];
      if (orig >= 0) out[orig] = 1.f / (1.f + expf(-(ys[r2] + addc)));
    }
  }
}

// ------------------------------------------------ launch
extern "C" void kernel_launch(void* const* d_in, const int* in_sizes, int n_in,
                              void* d_out, int out_size, void* d_ws, size_t ws_size,
                              hipStream_t stream) {
  (void)in_sizes; (void)n_in; (void)out_size; (void)ws_size;
  const float* x      = (const float*)d_in[0];
  const int*   dom    = (const int*)d_in[1];
  const float* pn_w   = (const float*)d_in[2];
  const float* pn_b   = (const float*)d_in[3];
  const float* cW1    = (const float*)d_in[4];
  const float* cb1    = (const float*)d_in[5];
  const float* cW2    = (const float*)d_in[6];
  const float* cb2    = (const float*)d_in[7];
  const float* cW3    = (const float*)d_in[8];
  const float* cb3    = (const float*)d_in[9];
  const float* dW1    = (const float*)d_in[10];
  const float* db1    = (const float*)d_in[11];
  const float* dW2    = (const float*)d_in[12];
  const float* db2    = (const float*)d_in[13];
  const float* dW3    = (const float*)d_in[14];
  const float* db3    = (const float*)d_in[15];
  const float* fW1    = (const float*)d_in[16];
  const float* fb1    = (const float*)d_in[17];
  const float* fW2    = (const float*)d_in[18];
  const float* fb2    = (const float*)d_in[19];
  const float* demb   = (const float*)d_in[20];
  const float* aW1    = (const float*)d_in[21];
  const float* ab1    = (const float*)d_in[22];
  const float* aW2    = (const float*)d_in[23];
  const float* ab2    = (const float*)d_in[24];
  float* out = (float*)d_out;

  char* w = (char*)d_ws;
  int*   cnt2   = (int*)(w + 0);        // [4]
  int*   pstart = (int*)(w + 32);       // [5]
  float* aux    = (float*)(w + 64);     // [4]
  int*   perm   = (int*)(w + 256);                     // [MPAD] -> 67840
  int*   rowpos = (int*)(w + 67840);                   // [NB]   -> 133376
  u8*    bufA   = (u8*)(w + 133376);                   // norm MPADx1024 fp8, then h2 MPADx512
  u8*    bufB   = (u8*)(w + 17434880);                 // h1 MPADx1024 fp8
  u8*    cW1t   = (u8*)(w + 34736384);
  u8*    cW2t   = (u8*)(w + 35260672);
  u8*    cW3t   = (u8*)(w + 35391744);
  u8*    dW1t   = (u8*)(w + 35424512);
  u8*    dW2t   = (u8*)(w + 37521664);
  u8*    dW3t   = (u8*)(w + 38045952);
  bf16*  fW1t   = (bf16*)(w + 38177024);               // 64x128 bf16 -> end 38193408

  k_histscan_aux<<<1, 1024, 0, stream>>>(dom, pstart, cnt2, perm, aux,
                                         demb, aW1, ab1, aW2, ab2);
  k_assign<<<64, 256, 0, stream>>>(dom, pstart, cnt2, perm, rowpos);
  k_ln<<<4096, 256, 0, stream>>>(x, dom, rowpos, pn_w, pn_b, bufA);
  k_wt_all<<<842, 256, 0, stream>>>(cW1, cW2, cW3, dW1, dW2, dW3, fW1,
                                    cW1t, cW2t, cW3t, dW1t, dW2t, dW3t, fW1t);

  // L1: norm(bufA) -> h1(bufB) : K=1024, Nh=512, relu, 8 col tiles, 264 row tiles
  k_gemm<<<2112, 256, 0, stream>>>(bufA, 1024, 0, 0, cW1t, dW1t, cb1, db1,
                                   bufB, 512, 1024, 1, pstart, 3);
  // L2: h1(bufB) -> h2(bufA) : K=512, Nh=256, relu, 4 col tiles
  k_gemm<<<1056, 256, 0, stream>>>(bufB, 1024, 0, 512, cW2t, dW2t, cb2, db2,
                                   bufA, 256, 512, 1, pstart, 2);
  // L3 + head fused: h2(bufA) -> out
  k_gemm3<<<264, 256, 0, stream>>>(bufA, cW3t, dW3t, cb3, db3, fW1t,
                                   fb1, fW2, fb2, perm, pstart, aux, out);
}